// Round 6
// baseline (285.451 us; speedup 1.0000x reference)
//
#include <hip/hip_runtime.h>
#include <hip/hip_bf16.h>

// GCNEncoder: 2-layer GCN, out-degree norm. N=100000, E=1600000, 128->128->64, fp32 I/O.
// R15: time ledger shows a stable ~190us outside {agg128, scatter2}; finalize (391 blocks,
// serial hist->scan->sort->2nd-hist) is the prime suspect (~40-60us, R13-scatter2 disease).
// Fix with the same medicine that fixed scatter2:
//  (a) finalize: split dst-sort and src-hist/deg into SEPARATE blocks (782 total), 1024 thr
//      -> serial makespan ~1/3.
//  (b) scatter2: CHUNK 8192 -> 4096 (782 heavy blocks, per-block loops halve; cursor atomics
//      ~200k, trivial; slight run-copy write-amp on 8MB payload, acceptable).
// Gathers/GEMMs/aliasing untouched for clean attribution.
// Predict: finalize ~45 -> ~20, scatter2 ~31 -> ~24, agg128 unchanged (top, 56.8),
// total 277.8 -> ~245-258.

typedef __attribute__((ext_vector_type(8))) short short8;
typedef __attribute__((ext_vector_type(4))) float floatx4;

__device__ inline unsigned short f2bf(float f) {
    union { float f; unsigned u; } v; v.f = f;
    return (unsigned short)((v.u + 0x8000u) >> 16);  // round-half-away; ties p~2^-17 vs RNE
}
__device__ inline float bf2f(unsigned b) {
    union { unsigned u; float f; } v; v.u = b << 16;
    return v.f;
}
__device__ inline float bf2f_hi(unsigned b) {
    union { unsigned u; float f; } v; v.u = b & 0xFFFF0000u;
    return v.f;
}

#define NBMAX 512   // max 256-node buckets -> N <= 131072 (src < 2^24 for packing)
#define CAP   8192  // fixed bucket capacity; mean 4092 + <=768 alignment pad -> safe
#define CHUNK 4096  // edges per scatter block (R15: halved for 2x block parallelism)

// ---- W preconvert fp32[k][n] -> bf16[n][k] for both layers; zero cnt_d|cnt_s cursors ----
__global__ __launch_bounds__(256) void convw_kernel(
    const float* __restrict__ W1, const float* __restrict__ W2,
    unsigned short* __restrict__ Wb1, unsigned short* __restrict__ Wb2,
    int* __restrict__ cnt)
{
    int i = blockIdx.x * 256 + threadIdx.x;
    if (i < NBMAX * 32) cnt[i] = 0;  // cnt_d | cnt_s (2 * NBMAX * 16 ints)
    if (i < 128 * 128) {
        int k = i >> 7, n = i & 127;
        Wb1[n * 128 + k] = f2bf(W1[k * 128 + n]);
    }
    i -= 128 * 128;
    if (i >= 0 && i < 128 * 64) {
        int k = i >> 6, n = i & 63;
        Wb2[n * 128 + k] = f2bf(W2[k * 64 + n]);
    }
}

// ---- pass 1: LDS-staged bucket partition; per-bucket run-copy write-out.
//      Blocks [0,EB): pairs by dst-bucket. [EB,2EB): src low-bytes by src-bucket.
//      Blocks >= 2EB: stream-convert x fp32 -> xb bf16. ----
__global__ __launch_bounds__(1024) void scatter2_kernel(
    const int* __restrict__ src, const int* __restrict__ dst, int E,
    int* __restrict__ cnt_d, int* __restrict__ cnt_s,
    unsigned* __restrict__ pairs, unsigned char* __restrict__ srcs_b, int NB,
    const float* __restrict__ x, unsigned short* __restrict__ xb, int NF8)
{
    const int EB = (E + CHUNK - 1) / CHUNK;
    const int t = threadIdx.x;
    const int bid = blockIdx.x;
    if (bid >= 2 * EB) {
        int i = (bid - 2 * EB) * 1024 + t;  // 8-float chunk id
        if (i < NF8) {
            float4 a0 = ((const float4*)x)[(size_t)i * 2];
            float4 a1 = ((const float4*)x)[(size_t)i * 2 + 1];
            uint4 st;
            st.x = (unsigned)f2bf(a0.x) | ((unsigned)f2bf(a0.y) << 16);
            st.y = (unsigned)f2bf(a0.z) | ((unsigned)f2bf(a0.w) << 16);
            st.z = (unsigned)f2bf(a1.x) | ((unsigned)f2bf(a1.y) << 16);
            st.w = (unsigned)f2bf(a1.z) | ((unsigned)f2bf(a1.w) << 16);
            ((uint4*)xb)[i] = st;
        }
        return;
    }
    __shared__ int hd[NBMAX], lb[NBMAX], bd[NBMAX], cd_[NBMAX];
    __shared__ unsigned staged[CHUNK];  // 16KB; low 4KB reused as bytes in phase B
    const bool phaseA = (bid < EB);
    const int c = phaseA ? bid : bid - EB;
    const int e0 = c * CHUNK;
    const int e1 = min(e0 + CHUNK, E);
    const int* __restrict__ key = phaseA ? dst : src;

    for (int i = t; i < NB; i += 1024) { hd[i] = 0; cd_[i] = 0; }
    __syncthreads();
    for (int i = e0 + t; i < e1; i += 1024)
        atomicAdd(&hd[key[i] >> 8], 1);
    __syncthreads();
    if (t < NBMAX) lb[t] = (t < NB) ? hd[t] : 0;
    __syncthreads();
    for (int o = 1; o < NBMAX; o <<= 1) {       // inclusive scan over NBMAX entries
        int add = (t >= o && t < NBMAX) ? lb[t - o] : 0;
        __syncthreads();
        if (t < NBMAX) lb[t] += add;
        __syncthreads();
    }
    int* __restrict__ gcnt = phaseA ? cnt_d : cnt_s;
    for (int i = t; i < NB; i += 1024)
        if (hd[i]) bd[i] = atomicAdd(&gcnt[i * 16], hd[i]);
    __syncthreads();

    const int wid = t >> 6, lane = t & 63;
    if (phaseA) {
        for (int i = e0 + t; i < e1; i += 1024) {
            int sv = src[i], dv = dst[i];
            int b = dv >> 8;
            int slot = atomicAdd(&cd_[b], 1);
            staged[lb[b] - hd[b] + slot] = ((unsigned)(dv & 255) << 24) | (unsigned)sv;
        }
        __syncthreads();
        for (int b = wid; b < NB; b += 16) {    // run-copy: wave per bucket
            int len = hd[b];
            if (!len) continue;
            int start = lb[b] - len;
            size_t gbase = (size_t)b * CAP + bd[b];
            for (int j = lane; j < len; j += 64)
                pairs[gbase + j] = staged[start + j];
        }
    } else {
        unsigned char* stb = (unsigned char*)staged;
        for (int i = e0 + t; i < e1; i += 1024) {
            int sv = src[i];
            int b = sv >> 8;
            int slot = atomicAdd(&cd_[b], 1);
            stb[lb[b] - hd[b] + slot] = (unsigned char)(sv & 255);
        }
        __syncthreads();
        for (int b = wid; b < NB; b += 16) {
            int len = hd[b];
            if (!len) continue;
            int start = lb[b] - len;
            size_t gbase = (size_t)b * CAP + bd[b];
            for (int j = lane; j < len; j += 64)
                srcs_b[gbase + j] = stb[start + j];
        }
    }
}

// ---- pass 2 (split roles, 1024 thr): blocks [0,NB): per-bucket dst sort (4-aligned
//      segments, pads -> dummy index N = zero row) -> sorted_src + (start,end);
//      blocks [NB,2NB): src-byte hist -> deg_inv. ----
__global__ __launch_bounds__(1024) void bucket_finalize_kernel(
    const unsigned* __restrict__ pairs, const unsigned char* __restrict__ srcs_b,
    const int* __restrict__ cnt_d, const int* __restrict__ cnt_s,
    int* __restrict__ sorted_src, int2* __restrict__ se,
    float* __restrict__ deg_inv, int N, int NB)
{
    const bool histRole = (int)blockIdx.x >= NB;
    const int b = histRole ? (int)blockIdx.x - NB : (int)blockIdx.x;
    const int node0 = b << 8;
    const int t = threadIdx.x;
    const size_t base = (size_t)b * CAP;
    __shared__ int hist[256];
    __shared__ int cur[256];
    __shared__ int pre[256];

    if (!histRole) {
        const int cd = cnt_d[b * 16];
        if (t < 256) hist[t] = 0;
        __syncthreads();
        for (int i = t; i < cd; i += 1024)
            atomicAdd(&hist[pairs[base + i] >> 24], 1);
        __syncthreads();
        int v = 0, v4 = 0;
        if (t < 256) {
            v = hist[t];
            v4 = (v + 3) & ~3;  // 4-edge aligned segments (16B int4 idx loads)
            pre[t] = v4;
        }
        __syncthreads();
        for (int o = 1; o < 256; o <<= 1) {
            int add = (t >= o && t < 256) ? pre[t - o] : 0;
            __syncthreads();
            if (t < 256) pre[t] += add;
            __syncthreads();
        }
        if (t < 256) {
            int excl = pre[t] - v4;
            cur[t] = excl;
            if (node0 + t < N) {
                se[node0 + t] = make_int2((int)base + excl, (int)base + excl + v);
                // fill alignment pad with dummy index N (zero row) -> no scalar agg tail
                for (int i = v; i < v4; ++i) sorted_src[base + excl + i] = N;
            }
        }
        __syncthreads();
        for (int i = t; i < cd; i += 1024) {
            unsigned p = pairs[base + i];
            int pos = atomicAdd(&cur[p >> 24], 1);
            sorted_src[base + pos] = (int)(p & 0xFFFFFFu);
        }
    } else {
        if (t < 256) hist[t] = 0;
        __syncthreads();
        const int cs = cnt_s[b * 16];
        for (int i = t; i < cs; i += 1024)
            atomicAdd(&hist[srcs_b[base + i]], 1);
        __syncthreads();
        if (t < 256 && node0 + t < N) {
            int d = hist[t];
            deg_inv[node0 + t] = 1.0f / (float)(d < 1 ? 1 : d);
        }
    }
}

// ---------------- MFMA GEMM, no LDS: per-lane A fragments straight from global ----------------
// 64 rows/block (4 waves x 16 rows). A bf16 [M x 128]. SC=1: deg_inv scale in epilogue.
// B = bf16 Wb[n][k], L1/L2-resident. Block 0 zeroes output row M (dummy row for agg pads).
template <int NC, int SC>
__global__ __launch_bounds__(256) void gemm_mfma_kernel(
    const unsigned short* __restrict__ Ab, const unsigned short* __restrict__ Wb,
    const float* __restrict__ scale, unsigned short* __restrict__ Cb, int M)
{
    constexpr int NT = NC / 16;
    const int t = threadIdx.x;
    if (blockIdx.x == 0 && t < NC / 2)
        ((unsigned*)Cb)[(size_t)M * (NC / 2) + t] = 0;  // zero dummy row M
    const int wm = t >> 6;
    const int lane = t & 63;
    const int lm = lane & 15;
    const int lk = (lane >> 4) * 8;

    const int r0 = blockIdx.x * 64 + wm * 16;
    int row = r0 + lm;
    if (row >= M) row = M - 1;  // clamp loads; stores are guarded

    floatx4 acc[NT];
#pragma unroll
    for (int j = 0; j < NT; ++j) acc[j] = (floatx4){0.f, 0.f, 0.f, 0.f};

#pragma unroll
    for (int kk = 0; kk < 4; ++kk) {
        const int kb = kk * 32 + lk;
        short8 af = *(const short8*)&Ab[(size_t)row * 128 + kb];
#pragma unroll
        for (int j = 0; j < NT; ++j) {
            short8 bfr = *(const short8*)&Wb[(size_t)(j * 16 + lm) * 128 + kb];
            acc[j] = __builtin_amdgcn_mfma_f32_16x16x32_bf16(af, bfr, acc[j], 0, 0, 0);
        }
    }

    const int rbase = r0 + (lane >> 4) * 4;
#pragma unroll
    for (int reg = 0; reg < 4; ++reg) {
        int rg = rbase + reg;
        if (rg < M) {
            float di = SC ? scale[rg] : 1.0f;
#pragma unroll
            for (int j = 0; j < NT; ++j)
                Cb[(size_t)rg * NC + j * 16 + lm] = f2bf(SC ? acc[j][reg] * di : acc[j][reg]);
        }
    }
}

// ---------------- aggregate C=128: half-wave/node, uint2 loads, 8-edge unroll + idx prefetch ----------------
// Epilogue: relu(. + b1) * deg_inv -> bf16 (deg_inv of NEXT layer's row folded here).
#define LD128(vv, ii) uint2 vv = *(const uint2*)&val[(size_t)(ii) * 64 + 2 * l]
#define ACC8_128(I0, I1) do { \
    LD128(v0, I0.x); LD128(v1, I0.y); LD128(v2, I0.z); LD128(v3, I0.w); \
    LD128(v4, I1.x); LD128(v5, I1.y); LD128(v6, I1.z); LD128(v7, I1.w); \
    a0 += ((bf2f(v0.x & 0xFFFF) + bf2f(v1.x & 0xFFFF)) + (bf2f(v2.x & 0xFFFF) + bf2f(v3.x & 0xFFFF))) \
        + ((bf2f(v4.x & 0xFFFF) + bf2f(v5.x & 0xFFFF)) + (bf2f(v6.x & 0xFFFF) + bf2f(v7.x & 0xFFFF))); \
    a1 += ((bf2f_hi(v0.x) + bf2f_hi(v1.x)) + (bf2f_hi(v2.x) + bf2f_hi(v3.x))) \
        + ((bf2f_hi(v4.x) + bf2f_hi(v5.x)) + (bf2f_hi(v6.x) + bf2f_hi(v7.x))); \
    a2 += ((bf2f(v0.y & 0xFFFF) + bf2f(v1.y & 0xFFFF)) + (bf2f(v2.y & 0xFFFF) + bf2f(v3.y & 0xFFFF))) \
        + ((bf2f(v4.y & 0xFFFF) + bf2f(v5.y & 0xFFFF)) + (bf2f(v6.y & 0xFFFF) + bf2f(v7.y & 0xFFFF))); \
    a3 += ((bf2f_hi(v0.y) + bf2f_hi(v1.y)) + (bf2f_hi(v2.y) + bf2f_hi(v3.y))) \
        + ((bf2f_hi(v4.y) + bf2f_hi(v5.y)) + (bf2f_hi(v6.y) + bf2f_hi(v7.y))); \
} while (0)
#define ACC4_128(I0) do { \
    LD128(v0, I0.x); LD128(v1, I0.y); LD128(v2, I0.z); LD128(v3, I0.w); \
    a0 += (bf2f(v0.x & 0xFFFF) + bf2f(v1.x & 0xFFFF)) + (bf2f(v2.x & 0xFFFF) + bf2f(v3.x & 0xFFFF)); \
    a1 += (bf2f_hi(v0.x) + bf2f_hi(v1.x)) + (bf2f_hi(v2.x) + bf2f_hi(v3.x)); \
    a2 += (bf2f(v0.y & 0xFFFF) + bf2f(v1.y & 0xFFFF)) + (bf2f(v2.y & 0xFFFF) + bf2f(v3.y & 0xFFFF)); \
    a3 += (bf2f_hi(v0.y) + bf2f_hi(v1.y)) + (bf2f_hi(v2.y) + bf2f_hi(v3.y)); \
} while (0)

__global__ __launch_bounds__(256) void aggregate128_kernel(
    const int2* __restrict__ se, const int* __restrict__ sorted_src,
    const unsigned* __restrict__ val, const float* __restrict__ bias,
    const float* __restrict__ deg_inv, unsigned* __restrict__ outb, int N)
{
    int node = blockIdx.x * 8 + (threadIdx.x >> 5);
    if (node >= N) return;
    int l = threadIdx.x & 31;
    int2 r = se[node];
    int e = r.x;
    const int end4 = r.x + ((r.y - r.x + 3) & ~3);  // pads -> zero row, safe to include
    float a0 = 0.f, a1 = 0.f, a2 = 0.f, a3 = 0.f;

    if (e + 8 <= end4) {
        int4 i0 = *(const int4*)&sorted_src[e];
        int4 i1 = *(const int4*)&sorted_src[e + 4];
        for (; e + 16 <= end4; e += 8) {
            int4 n0 = *(const int4*)&sorted_src[e + 8];
            int4 n1 = *(const int4*)&sorted_src[e + 12];
            ACC8_128(i0, i1);
            i0 = n0; i1 = n1;
        }
        ACC8_128(i0, i1);
        e += 8;
    }
    if (e < end4) {  // exactly 4 remain (segment length is a multiple of 4)
        int4 i0 = *(const int4*)&sorted_src[e];
        ACC4_128(i0);
    }

    float di = deg_inv[node];
    float4 bv = *(const float4*)&bias[4 * l];
    a0 = fmaxf(a0 + bv.x, 0.f) * di;
    a1 = fmaxf(a1 + bv.y, 0.f) * di;
    a2 = fmaxf(a2 + bv.z, 0.f) * di;
    a3 = fmaxf(a3 + bv.w, 0.f) * di;
    uint2 o;
    o.x = (unsigned)f2bf(a0) | ((unsigned)f2bf(a1) << 16);
    o.y = (unsigned)f2bf(a2) | ((unsigned)f2bf(a3) << 16);
    *(uint2*)&outb[(size_t)node * 64 + 2 * l] = o;
}

// ---------------- aggregate C=64 (bf16 in, fp32 out, +bias): 8-edge unroll + idx prefetch ----------------
#define LD64(vv, ii) unsigned vv = val[(size_t)(ii) * 32 + l]
#define ACC8_64(I0, I1) do { \
    LD64(v0, I0.x); LD64(v1, I0.y); LD64(v2, I0.z); LD64(v3, I0.w); \
    LD64(v4, I1.x); LD64(v5, I1.y); LD64(v6, I1.z); LD64(v7, I1.w); \
    ax += ((bf2f(v0 & 0xFFFF) + bf2f(v1 & 0xFFFF)) + (bf2f(v2 & 0xFFFF) + bf2f(v3 & 0xFFFF))) \
        + ((bf2f(v4 & 0xFFFF) + bf2f(v5 & 0xFFFF)) + (bf2f(v6 & 0xFFFF) + bf2f(v7 & 0xFFFF))); \
    ay += ((bf2f_hi(v0) + bf2f_hi(v1)) + (bf2f_hi(v2) + bf2f_hi(v3))) \
        + ((bf2f_hi(v4) + bf2f_hi(v5)) + (bf2f_hi(v6) + bf2f_hi(v7))); \
} while (0)
#define ACC4_64(I0) do { \
    LD64(v0, I0.x); LD64(v1, I0.y); LD64(v2, I0.z); LD64(v3, I0.w); \
    ax += (bf2f(v0 & 0xFFFF) + bf2f(v1 & 0xFFFF)) + (bf2f(v2 & 0xFFFF) + bf2f(v3 & 0xFFFF)); \
    ay += (bf2f_hi(v0) + bf2f_hi(v1)) + (bf2f_hi(v2) + bf2f_hi(v3)); \
} while (0)

__global__ __launch_bounds__(256) void aggregate64_kernel(
    const int2* __restrict__ se, const int* __restrict__ sorted_src,
    const unsigned* __restrict__ val, const float* __restrict__ bias,
    float* __restrict__ out, int N)
{
    int node = blockIdx.x * 8 + (threadIdx.x >> 5);
    if (node >= N) return;
    int l = threadIdx.x & 31;
    int2 r = se[node];
    int e = r.x;
    const int end4 = r.x + ((r.y - r.x + 3) & ~3);
    float ax = 0.f, ay = 0.f;

    if (e + 8 <= end4) {
        int4 i0 = *(const int4*)&sorted_src[e];
        int4 i1 = *(const int4*)&sorted_src[e + 4];
        for (; e + 16 <= end4; e += 8) {
            int4 n0 = *(const int4*)&sorted_src[e + 8];
            int4 n1 = *(const int4*)&sorted_src[e + 12];
            ACC8_64(i0, i1);
            i0 = n0; i1 = n1;
        }
        ACC8_64(i0, i1);
        e += 8;
    }
    if (e < end4) {
        int4 i0 = *(const int4*)&sorted_src[e];
        ACC4_64(i0);
    }

    float2 o = make_float2(ax + bias[2 * l], ay + bias[2 * l + 1]);
    *(float2*)&out[(size_t)node * 64 + 2 * l] = o;
}

extern "C" void kernel_launch(void* const* d_in, const int* in_sizes, int n_in,
                              void* d_out, int out_size, void* d_ws, size_t ws_size,
                              hipStream_t stream) {
    const float* x  = (const float*)d_in[0];
    const int*   ei = (const int*)d_in[1];
    const float* W1 = (const float*)d_in[2];
    const float* b1 = (const float*)d_in[3];
    const float* W2 = (const float*)d_in[4];
    const float* b2 = (const float*)d_in[5];
    float* out = (float*)d_out;

    const int N = in_sizes[0] / 128;
    const int E = in_sizes[1] / 2;
    const int* src = ei;
    const int* dst = ei + E;
    const int NB = (N + 255) >> 8;

    char* ws = (char*)d_ws;
    size_t off = 0;
    auto alloc = [&](size_t bytes) {
        void* p = ws + off;
        off = (off + bytes + 255) & ~(size_t)255;
        return p;
    };
    float* deg_inv  = (float*)alloc((size_t)N * 4);
    int2*  se       = (int2*)alloc((size_t)N * 8);
    int*   cnt_d    = (int*)alloc((size_t)NBMAX * 16 * 4 * 2);  // cnt_d | cnt_s adjacent
    int*   cnt_s    = cnt_d + (size_t)NBMAX * 16;
    unsigned short* Wb1 = (unsigned short*)alloc((size_t)128 * 128 * 2);
    unsigned short* Wb2 = (unsigned short*)alloc((size_t)64 * 128 * 2);
    unsigned*      pairs  = (unsigned*)alloc((size_t)NBMAX * CAP * 4);
    unsigned char* srcs_b = (unsigned char*)alloc((size_t)NBMAX * CAP);
    int*   sorted_src = (int*)alloc((size_t)NBMAX * CAP * 4);
    unsigned short* h    = (unsigned short*)alloc((size_t)(N + 1) * 128 * 2);  // +1: zero pad row
    unsigned short* out1 = (unsigned short*)alloc((size_t)N * 128 * 2);
    // xb (N x 128 bf16) aliases out1: xb written in scatter2, last read by gemm128;
    // out1 first written by aggregate128 (after gemm128) -> lifetimes disjoint.
    unsigned short* xb = out1;
    // g ((N+1) x 64 bf16) aliases pairs (dead after bucket_finalize) when it fits
    unsigned short* g = ((size_t)(N + 1) * 128 <= (size_t)NBMAX * CAP * 4)
                            ? (unsigned short*)pairs
                            : (unsigned short*)alloc((size_t)(N + 1) * 64 * 2);

    convw_kernel<<<96, 256, 0, stream>>>(W1, W2, Wb1, Wb2, cnt_d);

    const int EB = (E + CHUNK - 1) / CHUNK;
    const int NF8 = (N * 128) / 8;            // 8-float chunks (128 % 8 == 0)
    const int CB = (NF8 + 1023) / 1024;       // conversion tail blocks
    scatter2_kernel<<<2 * EB + CB, 1024, 0, stream>>>(src, dst, E, cnt_d, cnt_s,
                                                      pairs, srcs_b, NB, x, xb, NF8);
    bucket_finalize_kernel<<<2 * NB, 1024, 0, stream>>>(pairs, srcs_b, cnt_d, cnt_s,
                                                        sorted_src, se, deg_inv, N, NB);

    const int gblocks = (N + 63) / 64;
    const int ablocks = (N + 7) / 8;
    // layer 1: h = bf16(di * (xb @ W1)); out1 = bf16(relu(Agg(h)+b1) * di)
    gemm_mfma_kernel<128, 1><<<gblocks, 256, 0, stream>>>(xb, Wb1, deg_inv, h, N);
    aggregate128_kernel<<<ablocks, 256, 0, stream>>>(se, sorted_src, (const unsigned*)h, b1,
                                                     deg_inv, (unsigned*)out1, N);
    // layer 2: g = bf16(out1 @ W2); out = Agg(g) + b2
    gemm_mfma_kernel<64, 0><<<gblocks, 256, 0, stream>>>(out1, Wb2, nullptr, g, N);
    aggregate64_kernel<<<ablocks, 256, 0, stream>>>(se, sorted_src, (const unsigned*)g, b2, out, N);
}

// Round 7
// 271.511 us; speedup vs baseline: 1.0513x; 1.0513x over previous
//
#include <hip/hip_runtime.h>
#include <hip/hip_bf16.h>

// GCNEncoder: 2-layer GCN, out-degree norm. N=100000, E=1600000, 128->128->64, fp32 I/O.
// R16: (a) revert R15 (CHUNK back to 8192, fused 512-thr finalize) -- R15's halved chunks
// doubled per-chunk fixed costs with no parallelism gain (machine already full at 392 blocks).
// (b) FUSE gemm64 into aggregate128's epilogue: each block's 8x128 out1 tile goes to LDS
// (XOR-swizzled, M padded to 16 with zero rows), 4 waves do the 8x128 @ 128x64 via
// mfma_16x16x32_bf16 (4 K-steps each), write g directly. Deletes the out1 round-trip
// (25.6MB traffic) and the gemm64 dispatch.
// Predict: fused agg128 ~59-62us (WRITE 25->13MB, FETCH flat), total 285.5 -> ~266-273.

typedef __attribute__((ext_vector_type(8))) short short8;
typedef __attribute__((ext_vector_type(4))) float floatx4;

__device__ inline unsigned short f2bf(float f) {
    union { float f; unsigned u; } v; v.f = f;
    return (unsigned short)((v.u + 0x8000u) >> 16);  // round-half-away; ties p~2^-17 vs RNE
}
__device__ inline float bf2f(unsigned b) {
    union { unsigned u; float f; } v; v.u = b << 16;
    return v.f;
}
__device__ inline float bf2f_hi(unsigned b) {
    union { unsigned u; float f; } v; v.u = b & 0xFFFF0000u;
    return v.f;
}

#define NBMAX 512   // max 256-node buckets -> N <= 131072 (src < 2^24 for packing)
#define CAP   8192  // fixed bucket capacity; mean 4092 + <=768 alignment pad -> safe
#define CHUNK 8192  // edges per scatter block (R14-proven)

// ---- W preconvert fp32[k][n] -> bf16[n][k] for both layers; zero cnt_d|cnt_s cursors ----
__global__ __launch_bounds__(256) void convw_kernel(
    const float* __restrict__ W1, const float* __restrict__ W2,
    unsigned short* __restrict__ Wb1, unsigned short* __restrict__ Wb2,
    int* __restrict__ cnt)
{
    int i = blockIdx.x * 256 + threadIdx.x;
    if (i < NBMAX * 32) cnt[i] = 0;  // cnt_d | cnt_s (2 * NBMAX * 16 ints)
    if (i < 128 * 128) {
        int k = i >> 7, n = i & 127;
        Wb1[n * 128 + k] = f2bf(W1[k * 128 + n]);
    }
    i -= 128 * 128;
    if (i >= 0 && i < 128 * 64) {
        int k = i >> 6, n = i & 63;
        Wb2[n * 128 + k] = f2bf(W2[k * 64 + n]);
    }
}

// ---- pass 1: LDS-staged bucket partition; per-bucket run-copy write-out.
//      Blocks [0,EB): pairs by dst-bucket. [EB,2EB): src low-bytes by src-bucket.
//      Blocks >= 2EB: stream-convert x fp32 -> xb bf16. ----
__global__ __launch_bounds__(1024) void scatter2_kernel(
    const int* __restrict__ src, const int* __restrict__ dst, int E,
    int* __restrict__ cnt_d, int* __restrict__ cnt_s,
    unsigned* __restrict__ pairs, unsigned char* __restrict__ srcs_b, int NB,
    const float* __restrict__ x, unsigned short* __restrict__ xb, int NF8)
{
    const int EB = (E + CHUNK - 1) / CHUNK;
    const int t = threadIdx.x;
    const int bid = blockIdx.x;
    if (bid >= 2 * EB) {
        int i = (bid - 2 * EB) * 1024 + t;  // 8-float chunk id
        if (i < NF8) {
            float4 a0 = ((const float4*)x)[(size_t)i * 2];
            float4 a1 = ((const float4*)x)[(size_t)i * 2 + 1];
            uint4 st;
            st.x = (unsigned)f2bf(a0.x) | ((unsigned)f2bf(a0.y) << 16);
            st.y = (unsigned)f2bf(a0.z) | ((unsigned)f2bf(a0.w) << 16);
            st.z = (unsigned)f2bf(a1.x) | ((unsigned)f2bf(a1.y) << 16);
            st.w = (unsigned)f2bf(a1.z) | ((unsigned)f2bf(a1.w) << 16);
            ((uint4*)xb)[i] = st;
        }
        return;
    }
    __shared__ int hd[NBMAX], lb[NBMAX], bd[NBMAX], cd_[NBMAX];
    __shared__ unsigned staged[CHUNK];  // 32KB; low 8KB reused as bytes in phase B
    const bool phaseA = (bid < EB);
    const int c = phaseA ? bid : bid - EB;
    const int e0 = c * CHUNK;
    const int e1 = min(e0 + CHUNK, E);
    const int* __restrict__ key = phaseA ? dst : src;

    for (int i = t; i < NB; i += 1024) { hd[i] = 0; cd_[i] = 0; }
    __syncthreads();
    for (int i = e0 + t; i < e1; i += 1024)
        atomicAdd(&hd[key[i] >> 8], 1);
    __syncthreads();
    if (t < NBMAX) lb[t] = (t < NB) ? hd[t] : 0;
    __syncthreads();
    for (int o = 1; o < NBMAX; o <<= 1) {       // inclusive scan over NBMAX entries
        int add = (t >= o && t < NBMAX) ? lb[t - o] : 0;
        __syncthreads();
        if (t < NBMAX) lb[t] += add;
        __syncthreads();
    }
    int* __restrict__ gcnt = phaseA ? cnt_d : cnt_s;
    for (int i = t; i < NB; i += 1024)
        if (hd[i]) bd[i] = atomicAdd(&gcnt[i * 16], hd[i]);
    __syncthreads();

    const int wid = t >> 6, lane = t & 63;
    if (phaseA) {
        for (int i = e0 + t; i < e1; i += 1024) {
            int sv = src[i], dv = dst[i];
            int b = dv >> 8;
            int slot = atomicAdd(&cd_[b], 1);
            staged[lb[b] - hd[b] + slot] = ((unsigned)(dv & 255) << 24) | (unsigned)sv;
        }
        __syncthreads();
        for (int b = wid; b < NB; b += 16) {    // run-copy: wave per bucket
            int len = hd[b];
            if (!len) continue;
            int start = lb[b] - len;
            size_t gbase = (size_t)b * CAP + bd[b];
            for (int j = lane; j < len; j += 64)
                pairs[gbase + j] = staged[start + j];
        }
    } else {
        unsigned char* stb = (unsigned char*)staged;
        for (int i = e0 + t; i < e1; i += 1024) {
            int sv = src[i];
            int b = sv >> 8;
            int slot = atomicAdd(&cd_[b], 1);
            stb[lb[b] - hd[b] + slot] = (unsigned char)(sv & 255);
        }
        __syncthreads();
        for (int b = wid; b < NB; b += 16) {
            int len = hd[b];
            if (!len) continue;
            int start = lb[b] - len;
            size_t gbase = (size_t)b * CAP + bd[b];
            for (int j = lane; j < len; j += 64)
                srcs_b[gbase + j] = stb[start + j];
        }
    }
}

// ---- pass 2 (fused, 512 thr, R14-proven): per-bucket dst sort (4-aligned segments,
//      pads -> dummy index N = zero row) -> sorted_src + (start,end); src hist -> deg_inv ----
__global__ __launch_bounds__(512) void bucket_finalize_kernel(
    const unsigned* __restrict__ pairs, const unsigned char* __restrict__ srcs_b,
    const int* __restrict__ cnt_d, const int* __restrict__ cnt_s,
    int* __restrict__ sorted_src, int2* __restrict__ se,
    float* __restrict__ deg_inv, int N)
{
    const int b = blockIdx.x;
    const int node0 = b << 8;
    const int t = threadIdx.x;
    const size_t base = (size_t)b * CAP;
    __shared__ int hist[256];
    __shared__ int cur[256];
    __shared__ int pre[256];

    const int cd = cnt_d[b * 16];
    if (t < 256) hist[t] = 0;
    __syncthreads();
    for (int i = t; i < cd; i += 512)
        atomicAdd(&hist[pairs[base + i] >> 24], 1);
    __syncthreads();
    int v = 0, v4 = 0;
    if (t < 256) {
        v = hist[t];
        v4 = (v + 3) & ~3;  // 4-edge aligned segments (16B int4 idx loads)
        pre[t] = v4;
    }
    __syncthreads();
    for (int o = 1; o < 256; o <<= 1) {
        int add = (t >= o && t < 256) ? pre[t - o] : 0;
        __syncthreads();
        if (t < 256) pre[t] += add;
        __syncthreads();
    }
    if (t < 256) {
        int excl = pre[t] - v4;
        cur[t] = excl;
        if (node0 + t < N) {
            se[node0 + t] = make_int2((int)base + excl, (int)base + excl + v);
            // fill alignment pad with dummy index N (zero row) -> no scalar tail in aggregates
            for (int i = v; i < v4; ++i) sorted_src[base + excl + i] = N;
        }
    }
    __syncthreads();
    for (int i = t; i < cd; i += 512) {
        unsigned p = pairs[base + i];
        int pos = atomicAdd(&cur[p >> 24], 1);
        sorted_src[base + pos] = (int)(p & 0xFFFFFFu);
    }

    __syncthreads();
    if (t < 256) hist[t] = 0;
    __syncthreads();
    const int cs = cnt_s[b * 16];
    for (int i = t; i < cs; i += 512)
        atomicAdd(&hist[srcs_b[base + i]], 1);
    __syncthreads();
    if (t < 256 && node0 + t < N) {
        int d = hist[t];
        deg_inv[node0 + t] = 1.0f / (float)(d < 1 ? 1 : d);
    }
}

// ---------------- MFMA GEMM (layer 1 only), no LDS ----------------
// 64 rows/block (4 waves x 16 rows). A bf16 [M x 128]. deg_inv scale in epilogue.
// Block 0 zeroes output row M (dummy row for agg pads).
__global__ __launch_bounds__(256) void gemm_mfma_kernel(
    const unsigned short* __restrict__ Ab, const unsigned short* __restrict__ Wb,
    const float* __restrict__ scale, unsigned short* __restrict__ Cb, int M)
{
    constexpr int NC = 128, NT = NC / 16;
    const int t = threadIdx.x;
    if (blockIdx.x == 0 && t < NC / 2)
        ((unsigned*)Cb)[(size_t)M * (NC / 2) + t] = 0;  // zero dummy row M
    const int wm = t >> 6;
    const int lane = t & 63;
    const int lm = lane & 15;
    const int lk = (lane >> 4) * 8;

    const int r0 = blockIdx.x * 64 + wm * 16;
    int row = r0 + lm;
    if (row >= M) row = M - 1;  // clamp loads; stores are guarded

    floatx4 acc[NT];
#pragma unroll
    for (int j = 0; j < NT; ++j) acc[j] = (floatx4){0.f, 0.f, 0.f, 0.f};

#pragma unroll
    for (int kk = 0; kk < 4; ++kk) {
        const int kb = kk * 32 + lk;
        short8 af = *(const short8*)&Ab[(size_t)row * 128 + kb];
#pragma unroll
        for (int j = 0; j < NT; ++j) {
            short8 bfr = *(const short8*)&Wb[(size_t)(j * 16 + lm) * 128 + kb];
            acc[j] = __builtin_amdgcn_mfma_f32_16x16x32_bf16(af, bfr, acc[j], 0, 0, 0);
        }
    }

    const int rbase = r0 + (lane >> 4) * 4;
#pragma unroll
    for (int reg = 0; reg < 4; ++reg) {
        int rg = rbase + reg;
        if (rg < M) {
            float di = scale[rg];
#pragma unroll
            for (int j = 0; j < NT; ++j)
                Cb[(size_t)rg * NC + j * 16 + lm] = f2bf(acc[j][reg] * di);
        }
    }
}

// ---------------- aggregate C=128 FUSED with layer-2 GEMM ----------------
// Gather phase (per half-wave/node, 8-edge unroll + idx prefetch):
//   t[node] = relu(Agg(h)+b1) * deg_inv  (8x128 tile, kept in regs)
// Then tile -> LDS (XOR-swizzled, M padded to 16 w/ zero rows), 4 waves compute
// tile @ W2 via mfma_16x16x32_bf16 (wave w = N-tile w, 4 K-steps), store g bf16.
#define LD128(vv, ii) uint2 vv = *(const uint2*)&val[(size_t)(ii) * 64 + 2 * l]
#define ACC8_128(I0, I1) do { \
    LD128(v0, I0.x); LD128(v1, I0.y); LD128(v2, I0.z); LD128(v3, I0.w); \
    LD128(v4, I1.x); LD128(v5, I1.y); LD128(v6, I1.z); LD128(v7, I1.w); \
    a0 += ((bf2f(v0.x & 0xFFFF) + bf2f(v1.x & 0xFFFF)) + (bf2f(v2.x & 0xFFFF) + bf2f(v3.x & 0xFFFF))) \
        + ((bf2f(v4.x & 0xFFFF) + bf2f(v5.x & 0xFFFF)) + (bf2f(v6.x & 0xFFFF) + bf2f(v7.x & 0xFFFF))); \
    a1 += ((bf2f_hi(v0.x) + bf2f_hi(v1.x)) + (bf2f_hi(v2.x) + bf2f_hi(v3.x))) \
        + ((bf2f_hi(v4.x) + bf2f_hi(v5.x)) + (bf2f_hi(v6.x) + bf2f_hi(v7.x))); \
    a2 += ((bf2f(v0.y & 0xFFFF) + bf2f(v1.y & 0xFFFF)) + (bf2f(v2.y & 0xFFFF) + bf2f(v3.y & 0xFFFF))) \
        + ((bf2f(v4.y & 0xFFFF) + bf2f(v5.y & 0xFFFF)) + (bf2f(v6.y & 0xFFFF) + bf2f(v7.y & 0xFFFF))); \
    a3 += ((bf2f_hi(v0.y) + bf2f_hi(v1.y)) + (bf2f_hi(v2.y) + bf2f_hi(v3.y))) \
        + ((bf2f_hi(v4.y) + bf2f_hi(v5.y)) + (bf2f_hi(v6.y) + bf2f_hi(v7.y))); \
} while (0)
#define ACC4_128(I0) do { \
    LD128(v0, I0.x); LD128(v1, I0.y); LD128(v2, I0.z); LD128(v3, I0.w); \
    a0 += (bf2f(v0.x & 0xFFFF) + bf2f(v1.x & 0xFFFF)) + (bf2f(v2.x & 0xFFFF) + bf2f(v3.x & 0xFFFF)); \
    a1 += (bf2f_hi(v0.x) + bf2f_hi(v1.x)) + (bf2f_hi(v2.x) + bf2f_hi(v3.x)); \
    a2 += (bf2f(v0.y & 0xFFFF) + bf2f(v1.y & 0xFFFF)) + (bf2f(v2.y & 0xFFFF) + bf2f(v3.y & 0xFFFF)); \
    a3 += (bf2f_hi(v0.y) + bf2f_hi(v1.y)) + (bf2f_hi(v2.y) + bf2f_hi(v3.y)); \
} while (0)

__global__ __launch_bounds__(256) void agg128_gemm_kernel(
    const int2* __restrict__ se, const int* __restrict__ sorted_src,
    const unsigned* __restrict__ val, const float* __restrict__ bias,
    const float* __restrict__ deg_inv, const unsigned short* __restrict__ Wb2,
    unsigned short* __restrict__ g, int N)
{
    __shared__ unsigned short tile[16 * 128];  // 4KB; rows 8-15 stay zero (M pad)
    const int t = threadIdx.x;
    // zero pad rows 8..15 (uints 512..1023) + dummy g row N (block 0)
    ((unsigned*)tile)[512 + t] = 0;
    ((unsigned*)tile)[768 + t] = 0;
    if (blockIdx.x == 0 && t < 32) ((unsigned*)g)[(size_t)N * 32 + t] = 0;

    const int hw = t >> 5;                     // half-wave = node row 0..7
    const int l = t & 31;
    const int node = blockIdx.x * 8 + hw;
    float a0 = 0.f, a1 = 0.f, a2 = 0.f, a3 = 0.f;
    if (node < N) {
        int2 r = se[node];
        int e = r.x;
        const int end4 = r.x + ((r.y - r.x + 3) & ~3);  // pads -> zero row
        if (e + 8 <= end4) {
            int4 i0 = *(const int4*)&sorted_src[e];
            int4 i1 = *(const int4*)&sorted_src[e + 4];
            for (; e + 16 <= end4; e += 8) {
                int4 n0 = *(const int4*)&sorted_src[e + 8];
                int4 n1 = *(const int4*)&sorted_src[e + 12];
                ACC8_128(i0, i1);
                i0 = n0; i1 = n1;
            }
            ACC8_128(i0, i1);
            e += 8;
        }
        if (e < end4) {  // exactly 4 remain
            int4 i0 = *(const int4*)&sorted_src[e];
            ACC4_128(i0);
        }
        float di = deg_inv[node];
        float4 bv = *(const float4*)&bias[4 * l];
        a0 = fmaxf(a0 + bv.x, 0.f) * di;
        a1 = fmaxf(a1 + bv.y, 0.f) * di;
        a2 = fmaxf(a2 + bv.z, 0.f) * di;
        a3 = fmaxf(a3 + bv.w, 0.f) * di;
    }
    // stage bf16 tile row hw, channels 4l..4l+3, XOR-swizzled 16B blocks within row:
    // byte block (l>>1) ^ (hw&7); inner 8B half = l&1.
    {
        unsigned w0 = (unsigned)f2bf(a0) | ((unsigned)f2bf(a1) << 16);
        unsigned w1 = (unsigned)f2bf(a2) | ((unsigned)f2bf(a3) << 16);
        unsigned* p = (unsigned*)&tile[hw * 128 + ((((l >> 1) ^ hw) & 15) << 3) + (l & 1) * 4];
        p[0] = w0;
        p[1] = w1;
    }
    __syncthreads();

    // mini-GEMM: wave w -> output cols [16w,16w+16); rows 0..15 (8 real + 8 zero pad)
    const int w = t >> 6;
    const int lane = t & 63;
    const int lm = lane & 15;
    const int lk = (lane >> 4) * 8;
    floatx4 acc = (floatx4){0.f, 0.f, 0.f, 0.f};
#pragma unroll
    for (int kk = 0; kk < 4; ++kk) {
        const int kb = kk * 32 + lk;
        const int blk = ((kb >> 3) ^ (lm & 7)) & 15;   // un-swizzle A read
        short8 af = *(const short8*)&tile[lm * 128 + (blk << 3)];
        short8 bfr = *(const short8*)&Wb2[(size_t)(w * 16 + lm) * 128 + kb];
        acc = __builtin_amdgcn_mfma_f32_16x16x32_bf16(af, bfr, acc, 0, 0, 0);
    }
    const int rbase = (lane >> 4) * 4;
#pragma unroll
    for (int reg = 0; reg < 4; ++reg) {
        int r = rbase + reg;
        if (r < 8) {
            int nd = blockIdx.x * 8 + r;
            if (nd < N) g[(size_t)nd * 64 + w * 16 + lm] = f2bf(acc[reg]);
        }
    }
}

// ---------------- aggregate C=64 (bf16 in, fp32 out, +bias): 8-edge unroll + idx prefetch ----------------
#define LD64(vv, ii) unsigned vv = val[(size_t)(ii) * 32 + l]
#define ACC8_64(I0, I1) do { \
    LD64(v0, I0.x); LD64(v1, I0.y); LD64(v2, I0.z); LD64(v3, I0.w); \
    LD64(v4, I1.x); LD64(v5, I1.y); LD64(v6, I1.z); LD64(v7, I1.w); \
    ax += ((bf2f(v0 & 0xFFFF) + bf2f(v1 & 0xFFFF)) + (bf2f(v2 & 0xFFFF) + bf2f(v3 & 0xFFFF))) \
        + ((bf2f(v4 & 0xFFFF) + bf2f(v5 & 0xFFFF)) + (bf2f(v6 & 0xFFFF) + bf2f(v7 & 0xFFFF))); \
    ay += ((bf2f_hi(v0) + bf2f_hi(v1)) + (bf2f_hi(v2) + bf2f_hi(v3))) \
        + ((bf2f_hi(v4) + bf2f_hi(v5)) + (bf2f_hi(v6) + bf2f_hi(v7))); \
} while (0)
#define ACC4_64(I0) do { \
    LD64(v0, I0.x); LD64(v1, I0.y); LD64(v2, I0.z); LD64(v3, I0.w); \
    ax += (bf2f(v0 & 0xFFFF) + bf2f(v1 & 0xFFFF)) + (bf2f(v2 & 0xFFFF) + bf2f(v3 & 0xFFFF)); \
    ay += (bf2f_hi(v0) + bf2f_hi(v1)) + (bf2f_hi(v2) + bf2f_hi(v3)); \
} while (0)

__global__ __launch_bounds__(256) void aggregate64_kernel(
    const int2* __restrict__ se, const int* __restrict__ sorted_src,
    const unsigned* __restrict__ val, const float* __restrict__ bias,
    float* __restrict__ out, int N)
{
    int node = blockIdx.x * 8 + (threadIdx.x >> 5);
    if (node >= N) return;
    int l = threadIdx.x & 31;
    int2 r = se[node];
    int e = r.x;
    const int end4 = r.x + ((r.y - r.x + 3) & ~3);
    float ax = 0.f, ay = 0.f;

    if (e + 8 <= end4) {
        int4 i0 = *(const int4*)&sorted_src[e];
        int4 i1 = *(const int4*)&sorted_src[e + 4];
        for (; e + 16 <= end4; e += 8) {
            int4 n0 = *(const int4*)&sorted_src[e + 8];
            int4 n1 = *(const int4*)&sorted_src[e + 12];
            ACC8_64(i0, i1);
            i0 = n0; i1 = n1;
        }
        ACC8_64(i0, i1);
        e += 8;
    }
    if (e < end4) {
        int4 i0 = *(const int4*)&sorted_src[e];
        ACC4_64(i0);
    }

    float2 o = make_float2(ax + bias[2 * l], ay + bias[2 * l + 1]);
    *(float2*)&out[(size_t)node * 64 + 2 * l] = o;
}

extern "C" void kernel_launch(void* const* d_in, const int* in_sizes, int n_in,
                              void* d_out, int out_size, void* d_ws, size_t ws_size,
                              hipStream_t stream) {
    const float* x  = (const float*)d_in[0];
    const int*   ei = (const int*)d_in[1];
    const float* W1 = (const float*)d_in[2];
    const float* b1 = (const float*)d_in[3];
    const float* W2 = (const float*)d_in[4];
    const float* b2 = (const float*)d_in[5];
    float* out = (float*)d_out;

    const int N = in_sizes[0] / 128;
    const int E = in_sizes[1] / 2;
    const int* src = ei;
    const int* dst = ei + E;
    const int NB = (N + 255) >> 8;

    char* ws = (char*)d_ws;
    size_t off = 0;
    auto alloc = [&](size_t bytes) {
        void* p = ws + off;
        off = (off + bytes + 255) & ~(size_t)255;
        return p;
    };
    float* deg_inv  = (float*)alloc((size_t)N * 4);
    int2*  se       = (int2*)alloc((size_t)N * 8);
    int*   cnt_d    = (int*)alloc((size_t)NBMAX * 16 * 4 * 2);  // cnt_d | cnt_s adjacent
    int*   cnt_s    = cnt_d + (size_t)NBMAX * 16;
    unsigned short* Wb1 = (unsigned short*)alloc((size_t)128 * 128 * 2);
    unsigned short* Wb2 = (unsigned short*)alloc((size_t)64 * 128 * 2);
    unsigned*      pairs  = (unsigned*)alloc((size_t)NBMAX * CAP * 4);
    unsigned char* srcs_b = (unsigned char*)alloc((size_t)NBMAX * CAP);
    int*   sorted_src = (int*)alloc((size_t)NBMAX * CAP * 4);
    unsigned short* h  = (unsigned short*)alloc((size_t)(N + 1) * 128 * 2);  // +1: zero pad row
    unsigned short* xb = (unsigned short*)alloc((size_t)N * 128 * 2);
    // g ((N+1) x 64 bf16) aliases pairs (dead after bucket_finalize) when it fits
    unsigned short* g = ((size_t)(N + 1) * 128 <= (size_t)NBMAX * CAP * 4)
                            ? (unsigned short*)pairs
                            : (unsigned short*)alloc((size_t)(N + 1) * 64 * 2);

    convw_kernel<<<96, 256, 0, stream>>>(W1, W2, Wb1, Wb2, cnt_d);

    const int EB = (E + CHUNK - 1) / CHUNK;
    const int NF8 = (N * 128) / 8;            // 8-float chunks (128 % 8 == 0)
    const int CB = (NF8 + 1023) / 1024;       // conversion tail blocks
    scatter2_kernel<<<2 * EB + CB, 1024, 0, stream>>>(src, dst, E, cnt_d, cnt_s,
                                                      pairs, srcs_b, NB, x, xb, NF8);
    bucket_finalize_kernel<<<NB, 512, 0, stream>>>(pairs, srcs_b, cnt_d, cnt_s,
                                                   sorted_src, se, deg_inv, N);

    const int gblocks = (N + 63) / 64;
    const int ablocks = (N + 7) / 8;
    // layer 1: h = bf16(di * (xb @ W1))
    gemm_mfma_kernel<<<gblocks, 256, 0, stream>>>(xb, Wb1, deg_inv, h, N);
    // fused: per block, tile = relu(Agg(h)+b1)*di ; g = tile @ W2 (out1 never hits memory)
    agg128_gemm_kernel<<<ablocks, 256, 0, stream>>>(se, sorted_src, (const unsigned*)h, b1,
                                                    deg_inv, Wb2, g, N);
    // layer 2: out = Agg(g) + b2
    aggregate64_kernel<<<ablocks, 256, 0, stream>>>(se, sorted_src, (const unsigned*)g, b2, out, N);
}

// Round 9
// 265.928 us; speedup vs baseline: 1.0734x; 1.0210x over previous
//
#include <hip/hip_runtime.h>
#include <hip/hip_bf16.h>

// GCNEncoder: 2-layer GCN, out-degree norm. N=100000, E=1600000, 128->128->64, fp32 I/O.
// R18 = R17 resubmit after infra failure, with two safety fixes:
//  (1) hipMemsetAsync removed (only new API call in the failing run; graph-capture risk) ->
//      tiny zero_cnt kernel (32 blocks) restores proven-safe pure-kernel launches.
//  (2) finalize LDS guard fixed: ss[] is written up to cd+768 (pad slots), so the staged
//      path requires cd <= SCAP-768 (was cd <= SCAP: latent overflow).
// Unchanged from R17: W1/W2 bf16 transpose in scatter2 tail blocks (convw dispatch deleted),
// LDS-staged finalize sort (kills 2nd 6.4MB global pairs pass), R16 fused agg128+gemm64,
// R14 scatter2 CHUNK=8192, pad->dummy-row, g-aliases-pairs.
// Predict: finalize -4-8us vs R16, agg128_gemm ~73us top (WRITE ~12.5MB), total -> ~258-266.

typedef __attribute__((ext_vector_type(8))) short short8;
typedef __attribute__((ext_vector_type(4))) float floatx4;

__device__ inline unsigned short f2bf(float f) {
    union { float f; unsigned u; } v; v.f = f;
    return (unsigned short)((v.u + 0x8000u) >> 16);  // round-half-away; ties p~2^-17 vs RNE
}
__device__ inline float bf2f(unsigned b) {
    union { unsigned u; float f; } v; v.u = b << 16;
    return v.f;
}
__device__ inline float bf2f_hi(unsigned b) {
    union { unsigned u; float f; } v; v.u = b & 0xFFFF0000u;
    return v.f;
}

#define NBMAX 512   // max 256-node buckets -> N <= 131072 (src < 2^24 for packing)
#define CAP   8192  // fixed bucket capacity; mean 4092 + <=768 alignment pad -> safe
#define CHUNK 8192  // edges per scatter block (R14-proven)
#define SCAP  6144  // LDS staging capacity in finalize (staged path needs cd <= SCAP-768)

// ---- zero bucket cursors (cnt_d | cnt_s contiguous: 2 * NBMAX * 16 ints) ----
__global__ __launch_bounds__(256) void zero_cnt_kernel(int* __restrict__ cnt)
{
    int i = blockIdx.x * 256 + threadIdx.x;
    if (i < NBMAX * 32) cnt[i] = 0;
}

// ---- pass 1: LDS-staged bucket partition; per-bucket run-copy write-out.
//      Blocks [0,EB): pairs by dst-bucket. [EB,2EB): src low-bytes by src-bucket.
//      Blocks >= 2EB: stream-convert x fp32 -> xb bf16, then W1/W2 -> bf16 [n][k]. ----
__global__ __launch_bounds__(1024) void scatter2_kernel(
    const int* __restrict__ src, const int* __restrict__ dst, int E,
    int* __restrict__ cnt_d, int* __restrict__ cnt_s,
    unsigned* __restrict__ pairs, unsigned char* __restrict__ srcs_b, int NB,
    const float* __restrict__ x, unsigned short* __restrict__ xb, int NF8,
    const float* __restrict__ W1, const float* __restrict__ W2,
    unsigned short* __restrict__ Wb1, unsigned short* __restrict__ Wb2)
{
    const int EB = (E + CHUNK - 1) / CHUNK;
    const int t = threadIdx.x;
    const int bid = blockIdx.x;
    if (bid >= 2 * EB) {
        int i = (bid - 2 * EB) * 1024 + t;  // 8-float chunk id
        if (i < NF8) {
            float4 a0 = ((const float4*)x)[(size_t)i * 2];
            float4 a1 = ((const float4*)x)[(size_t)i * 2 + 1];
            uint4 st;
            st.x = (unsigned)f2bf(a0.x) | ((unsigned)f2bf(a0.y) << 16);
            st.y = (unsigned)f2bf(a0.z) | ((unsigned)f2bf(a0.w) << 16);
            st.z = (unsigned)f2bf(a1.x) | ((unsigned)f2bf(a1.y) << 16);
            st.w = (unsigned)f2bf(a1.z) | ((unsigned)f2bf(a1.w) << 16);
            ((uint4*)xb)[i] = st;
        } else {
            int j = i - NF8;                 // W conversion (consumed by later kernels)
            if (j < 128 * 128) {
                int k = j >> 7, n = j & 127;
                Wb1[n * 128 + k] = f2bf(W1[k * 128 + n]);
            } else {
                j -= 128 * 128;
                if (j < 128 * 64) {
                    int k = j >> 6, n = j & 63;
                    Wb2[n * 128 + k] = f2bf(W2[k * 64 + n]);
                }
            }
        }
        return;
    }
    __shared__ int hd[NBMAX], lb[NBMAX], bd[NBMAX], cd_[NBMAX];
    __shared__ unsigned staged[CHUNK];  // 32KB; low 8KB reused as bytes in phase B
    const bool phaseA = (bid < EB);
    const int c = phaseA ? bid : bid - EB;
    const int e0 = c * CHUNK;
    const int e1 = min(e0 + CHUNK, E);
    const int* __restrict__ key = phaseA ? dst : src;

    for (int i = t; i < NB; i += 1024) { hd[i] = 0; cd_[i] = 0; }
    __syncthreads();
    for (int i = e0 + t; i < e1; i += 1024)
        atomicAdd(&hd[key[i] >> 8], 1);
    __syncthreads();
    if (t < NBMAX) lb[t] = (t < NB) ? hd[t] : 0;
    __syncthreads();
    for (int o = 1; o < NBMAX; o <<= 1) {       // inclusive scan over NBMAX entries
        int add = (t >= o && t < NBMAX) ? lb[t - o] : 0;
        __syncthreads();
        if (t < NBMAX) lb[t] += add;
        __syncthreads();
    }
    int* __restrict__ gcnt = phaseA ? cnt_d : cnt_s;
    for (int i = t; i < NB; i += 1024)
        if (hd[i]) bd[i] = atomicAdd(&gcnt[i * 16], hd[i]);
    __syncthreads();

    const int wid = t >> 6, lane = t & 63;
    if (phaseA) {
        for (int i = e0 + t; i < e1; i += 1024) {
            int sv = src[i], dv = dst[i];
            int b = dv >> 8;
            int slot = atomicAdd(&cd_[b], 1);
            staged[lb[b] - hd[b] + slot] = ((unsigned)(dv & 255) << 24) | (unsigned)sv;
        }
        __syncthreads();
        for (int b = wid; b < NB; b += 16) {    // run-copy: wave per bucket
            int len = hd[b];
            if (!len) continue;
            int start = lb[b] - len;
            size_t gbase = (size_t)b * CAP + bd[b];
            for (int j = lane; j < len; j += 64)
                pairs[gbase + j] = staged[start + j];
        }
    } else {
        unsigned char* stb = (unsigned char*)staged;
        for (int i = e0 + t; i < e1; i += 1024) {
            int sv = src[i];
            int b = sv >> 8;
            int slot = atomicAdd(&cd_[b], 1);
            stb[lb[b] - hd[b] + slot] = (unsigned char)(sv & 255);
        }
        __syncthreads();
        for (int b = wid; b < NB; b += 16) {
            int len = hd[b];
            if (!len) continue;
            int start = lb[b] - len;
            size_t gbase = (size_t)b * CAP + bd[b];
            for (int j = lane; j < len; j += 64)
                srcs_b[gbase + j] = stb[start + j];
        }
    }
}

// ---- pass 2 (fused, 512 thr): LDS-staged per-bucket dst sort (4-aligned segments,
//      pads -> dummy index N = zero row) -> sorted_src + (start,end); src hist -> deg_inv ----
__global__ __launch_bounds__(512) void bucket_finalize_kernel(
    const unsigned* __restrict__ pairs, const unsigned char* __restrict__ srcs_b,
    const int* __restrict__ cnt_d, const int* __restrict__ cnt_s,
    int* __restrict__ sorted_src, int2* __restrict__ se,
    float* __restrict__ deg_inv, int N)
{
    const int b = blockIdx.x;
    const int node0 = b << 8;
    const int t = threadIdx.x;
    const size_t base = (size_t)b * CAP;
    __shared__ int hist[256];
    __shared__ int cur[256];
    __shared__ int pre[256];
    __shared__ unsigned ps[SCAP];  // staged pairs (24KB)
    __shared__ int ss[SCAP];       // locally sorted incl. pads (24KB)

    const int cd = cnt_d[b * 16];
    const bool fits = (cd <= SCAP - 768);  // pads add up to 3*256 slots to ss[]
    if (t < 256) hist[t] = 0;
    __syncthreads();
    if (fits) {
        for (int i = t; i < cd; i += 512) {
            unsigned p = pairs[base + i];
            ps[i] = p;
            atomicAdd(&hist[p >> 24], 1);
        }
    } else {
        for (int i = t; i < cd; i += 512)
            atomicAdd(&hist[pairs[base + i] >> 24], 1);
    }
    __syncthreads();
    int v = 0, v4 = 0;
    if (t < 256) {
        v = hist[t];
        v4 = (v + 3) & ~3;  // 4-edge aligned segments (16B int4 idx loads)
        pre[t] = v4;
    }
    __syncthreads();
    for (int o = 1; o < 256; o <<= 1) {
        int add = (t >= o && t < 256) ? pre[t - o] : 0;
        __syncthreads();
        if (t < 256) pre[t] += add;
        __syncthreads();
    }
    int excl = 0;
    if (t < 256) {
        excl = pre[t] - v4;
        cur[t] = excl;
        if (node0 + t < N)
            se[node0 + t] = make_int2((int)base + excl, (int)base + excl + v);
    }
    __syncthreads();
    const int tot4 = pre[255];  // padded total (multiple of 4), <= cd + 3*256
    if (fits) {
        if (t < 256)
            for (int i = v; i < v4; ++i) ss[excl + i] = N;  // pads -> dummy zero row
        __syncthreads();
        for (int i = t; i < cd; i += 512) {
            unsigned p = ps[i];
            int pos = atomicAdd(&cur[p >> 24], 1);
            ss[pos] = (int)(p & 0xFFFFFFu);
        }
        __syncthreads();
        for (int i = t; i < tot4; i += 512)   // coalesced write-out
            sorted_src[base + i] = ss[i];
    } else {
        if (t < 256)
            for (int i = v; i < v4; ++i) sorted_src[base + excl + i] = N;
        __syncthreads();
        for (int i = t; i < cd; i += 512) {
            unsigned p = pairs[base + i];
            int pos = atomicAdd(&cur[p >> 24], 1);
            sorted_src[base + pos] = (int)(p & 0xFFFFFFu);
        }
    }

    __syncthreads();
    if (t < 256) hist[t] = 0;
    __syncthreads();
    const int cs = cnt_s[b * 16];
    for (int i = t; i < cs; i += 512)
        atomicAdd(&hist[srcs_b[base + i]], 1);
    __syncthreads();
    if (t < 256 && node0 + t < N) {
        int d = hist[t];
        deg_inv[node0 + t] = 1.0f / (float)(d < 1 ? 1 : d);
    }
}

// ---------------- MFMA GEMM (layer 1 only), no LDS ----------------
// 64 rows/block (4 waves x 16 rows). A bf16 [M x 128]. deg_inv scale in epilogue.
// Block 0 zeroes output row M (dummy row for agg pads).
__global__ __launch_bounds__(256) void gemm_mfma_kernel(
    const unsigned short* __restrict__ Ab, const unsigned short* __restrict__ Wb,
    const float* __restrict__ scale, unsigned short* __restrict__ Cb, int M)
{
    constexpr int NC = 128, NT = NC / 16;
    const int t = threadIdx.x;
    if (blockIdx.x == 0 && t < NC / 2)
        ((unsigned*)Cb)[(size_t)M * (NC / 2) + t] = 0;  // zero dummy row M
    const int wm = t >> 6;
    const int lane = t & 63;
    const int lm = lane & 15;
    const int lk = (lane >> 4) * 8;

    const int r0 = blockIdx.x * 64 + wm * 16;
    int row = r0 + lm;
    if (row >= M) row = M - 1;  // clamp loads; stores are guarded

    floatx4 acc[NT];
#pragma unroll
    for (int j = 0; j < NT; ++j) acc[j] = (floatx4){0.f, 0.f, 0.f, 0.f};

#pragma unroll
    for (int kk = 0; kk < 4; ++kk) {
        const int kb = kk * 32 + lk;
        short8 af = *(const short8*)&Ab[(size_t)row * 128 + kb];
#pragma unroll
        for (int j = 0; j < NT; ++j) {
            short8 bfr = *(const short8*)&Wb[(size_t)(j * 16 + lm) * 128 + kb];
            acc[j] = __builtin_amdgcn_mfma_f32_16x16x32_bf16(af, bfr, acc[j], 0, 0, 0);
        }
    }

    const int rbase = r0 + (lane >> 4) * 4;
#pragma unroll
    for (int reg = 0; reg < 4; ++reg) {
        int rg = rbase + reg;
        if (rg < M) {
            float di = scale[rg];
#pragma unroll
            for (int j = 0; j < NT; ++j)
                Cb[(size_t)rg * NC + j * 16 + lm] = f2bf(acc[j][reg] * di);
        }
    }
}

// ---------------- aggregate C=128 FUSED with layer-2 GEMM (R16-proven) ----------------
#define LD128(vv, ii) uint2 vv = *(const uint2*)&val[(size_t)(ii) * 64 + 2 * l]
#define ACC8_128(I0, I1) do { \
    LD128(v0, I0.x); LD128(v1, I0.y); LD128(v2, I0.z); LD128(v3, I0.w); \
    LD128(v4, I1.x); LD128(v5, I1.y); LD128(v6, I1.z); LD128(v7, I1.w); \
    a0 += ((bf2f(v0.x & 0xFFFF) + bf2f(v1.x & 0xFFFF)) + (bf2f(v2.x & 0xFFFF) + bf2f(v3.x & 0xFFFF))) \
        + ((bf2f(v4.x & 0xFFFF) + bf2f(v5.x & 0xFFFF)) + (bf2f(v6.x & 0xFFFF) + bf2f(v7.x & 0xFFFF))); \
    a1 += ((bf2f_hi(v0.x) + bf2f_hi(v1.x)) + (bf2f_hi(v2.x) + bf2f_hi(v3.x))) \
        + ((bf2f_hi(v4.x) + bf2f_hi(v5.x)) + (bf2f_hi(v6.x) + bf2f_hi(v7.x))); \
    a2 += ((bf2f(v0.y & 0xFFFF) + bf2f(v1.y & 0xFFFF)) + (bf2f(v2.y & 0xFFFF) + bf2f(v3.y & 0xFFFF))) \
        + ((bf2f(v4.y & 0xFFFF) + bf2f(v5.y & 0xFFFF)) + (bf2f(v6.y & 0xFFFF) + bf2f(v7.y & 0xFFFF))); \
    a3 += ((bf2f_hi(v0.y) + bf2f_hi(v1.y)) + (bf2f_hi(v2.y) + bf2f_hi(v3.y))) \
        + ((bf2f_hi(v4.y) + bf2f_hi(v5.y)) + (bf2f_hi(v6.y) + bf2f_hi(v7.y))); \
} while (0)
#define ACC4_128(I0) do { \
    LD128(v0, I0.x); LD128(v1, I0.y); LD128(v2, I0.z); LD128(v3, I0.w); \
    a0 += (bf2f(v0.x & 0xFFFF) + bf2f(v1.x & 0xFFFF)) + (bf2f(v2.x & 0xFFFF) + bf2f(v3.x & 0xFFFF)); \
    a1 += (bf2f_hi(v0.x) + bf2f_hi(v1.x)) + (bf2f_hi(v2.x) + bf2f_hi(v3.x)); \
    a2 += (bf2f(v0.y & 0xFFFF) + bf2f(v1.y & 0xFFFF)) + (bf2f(v2.y & 0xFFFF) + bf2f(v3.y & 0xFFFF)); \
    a3 += (bf2f_hi(v0.y) + bf2f_hi(v1.y)) + (bf2f_hi(v2.y) + bf2f_hi(v3.y)); \
} while (0)

__global__ __launch_bounds__(256) void agg128_gemm_kernel(
    const int2* __restrict__ se, const int* __restrict__ sorted_src,
    const unsigned* __restrict__ val, const float* __restrict__ bias,
    const float* __restrict__ deg_inv, const unsigned short* __restrict__ Wb2,
    unsigned short* __restrict__ g, int N)
{
    __shared__ unsigned short tile[16 * 128];  // 4KB; rows 8-15 stay zero (M pad)
    const int t = threadIdx.x;
    ((unsigned*)tile)[512 + t] = 0;
    ((unsigned*)tile)[768 + t] = 0;
    if (blockIdx.x == 0 && t < 32) ((unsigned*)g)[(size_t)N * 32 + t] = 0;

    const int hw = t >> 5;                     // half-wave = node row 0..7
    const int l = t & 31;
    const int node = blockIdx.x * 8 + hw;
    float a0 = 0.f, a1 = 0.f, a2 = 0.f, a3 = 0.f;
    if (node < N) {
        int2 r = se[node];
        int e = r.x;
        const int end4 = r.x + ((r.y - r.x + 3) & ~3);  // pads -> zero row
        if (e + 8 <= end4) {
            int4 i0 = *(const int4*)&sorted_src[e];
            int4 i1 = *(const int4*)&sorted_src[e + 4];
            for (; e + 16 <= end4; e += 8) {
                int4 n0 = *(const int4*)&sorted_src[e + 8];
                int4 n1 = *(const int4*)&sorted_src[e + 12];
                ACC8_128(i0, i1);
                i0 = n0; i1 = n1;
            }
            ACC8_128(i0, i1);
            e += 8;
        }
        if (e < end4) {  // exactly 4 remain
            int4 i0 = *(const int4*)&sorted_src[e];
            ACC4_128(i0);
        }
        float di = deg_inv[node];
        float4 bv = *(const float4*)&bias[4 * l];
        a0 = fmaxf(a0 + bv.x, 0.f) * di;
        a1 = fmaxf(a1 + bv.y, 0.f) * di;
        a2 = fmaxf(a2 + bv.z, 0.f) * di;
        a3 = fmaxf(a3 + bv.w, 0.f) * di;
    }
    // stage bf16 tile row hw, channels 4l..4l+3, XOR-swizzled 16B blocks within row
    {
        unsigned w0 = (unsigned)f2bf(a0) | ((unsigned)f2bf(a1) << 16);
        unsigned w1 = (unsigned)f2bf(a2) | ((unsigned)f2bf(a3) << 16);
        unsigned* p = (unsigned*)&tile[hw * 128 + ((((l >> 1) ^ hw) & 15) << 3) + (l & 1) * 4];
        p[0] = w0;
        p[1] = w1;
    }
    __syncthreads();

    // mini-GEMM: wave w -> output cols [16w,16w+16); rows 0..15 (8 real + 8 zero pad)
    const int w = t >> 6;
    const int lane = t & 63;
    const int lm = lane & 15;
    const int lk = (lane >> 4) * 8;
    floatx4 acc = (floatx4){0.f, 0.f, 0.f, 0.f};
#pragma unroll
    for (int kk = 0; kk < 4; ++kk) {
        const int kb = kk * 32 + lk;
        const int blk = ((kb >> 3) ^ (lm & 7)) & 15;   // un-swizzle A read
        short8 af = *(const short8*)&tile[lm * 128 + (blk << 3)];
        short8 bfr = *(const short8*)&Wb2[(size_t)(w * 16 + lm) * 128 + kb];
        acc = __builtin_amdgcn_mfma_f32_16x16x32_bf16(af, bfr, acc, 0, 0, 0);
    }
    const int rbase = (lane >> 4) * 4;
#pragma unroll
    for (int reg = 0; reg < 4; ++reg) {
        int r = rbase + reg;
        if (r < 8) {
            int nd = blockIdx.x * 8 + r;
            if (nd < N) g[(size_t)nd * 64 + w * 16 + lm] = f2bf(acc[reg]);
        }
    }
}

// ---------------- aggregate C=64 (bf16 in, fp32 out, +bias): 8-edge unroll + idx prefetch ----------------
#define LD64(vv, ii) unsigned vv = val[(size_t)(ii) * 32 + l]
#define ACC8_64(I0, I1) do { \
    LD64(v0, I0.x); LD64(v1, I0.y); LD64(v2, I0.z); LD64(v3, I0.w); \
    LD64(v4, I1.x); LD64(v5, I1.y); LD64(v6, I1.z); LD64(v7, I1.w); \
    ax += ((bf2f(v0 & 0xFFFF) + bf2f(v1 & 0xFFFF)) + (bf2f(v2 & 0xFFFF) + bf2f(v3 & 0xFFFF))) \
        + ((bf2f(v4 & 0xFFFF) + bf2f(v5 & 0xFFFF)) + (bf2f(v6 & 0xFFFF) + bf2f(v7 & 0xFFFF))); \
    ay += ((bf2f_hi(v0) + bf2f_hi(v1)) + (bf2f_hi(v2) + bf2f_hi(v3))) \
        + ((bf2f_hi(v4) + bf2f_hi(v5)) + (bf2f_hi(v6) + bf2f_hi(v7))); \
} while (0)
#define ACC4_64(I0) do { \
    LD64(v0, I0.x); LD64(v1, I0.y); LD64(v2, I0.z); LD64(v3, I0.w); \
    ax += (bf2f(v0 & 0xFFFF) + bf2f(v1 & 0xFFFF)) + (bf2f(v2 & 0xFFFF) + bf2f(v3 & 0xFFFF)); \
    ay += (bf2f_hi(v0) + bf2f_hi(v1)) + (bf2f_hi(v2) + bf2f_hi(v3)); \
} while (0)

__global__ __launch_bounds__(256) void aggregate64_kernel(
    const int2* __restrict__ se, const int* __restrict__ sorted_src,
    const unsigned* __restrict__ val, const float* __restrict__ bias,
    float* __restrict__ out, int N)
{
    int node = blockIdx.x * 8 + (threadIdx.x >> 5);
    if (node >= N) return;
    int l = threadIdx.x & 31;
    int2 r = se[node];
    int e = r.x;
    const int end4 = r.x + ((r.y - r.x + 3) & ~3);
    float ax = 0.f, ay = 0.f;

    if (e + 8 <= end4) {
        int4 i0 = *(const int4*)&sorted_src[e];
        int4 i1 = *(const int4*)&sorted_src[e + 4];
        for (; e + 16 <= end4; e += 8) {
            int4 n0 = *(const int4*)&sorted_src[e + 8];
            int4 n1 = *(const int4*)&sorted_src[e + 12];
            ACC8_64(i0, i1);
            i0 = n0; i1 = n1;
        }
        ACC8_64(i0, i1);
        e += 8;
    }
    if (e < end4) {
        int4 i0 = *(const int4*)&sorted_src[e];
        ACC4_64(i0);
    }

    float2 o = make_float2(ax + bias[2 * l], ay + bias[2 * l + 1]);
    *(float2*)&out[(size_t)node * 64 + 2 * l] = o;
}

extern "C" void kernel_launch(void* const* d_in, const int* in_sizes, int n_in,
                              void* d_out, int out_size, void* d_ws, size_t ws_size,
                              hipStream_t stream) {
    const float* x  = (const float*)d_in[0];
    const int*   ei = (const int*)d_in[1];
    const float* W1 = (const float*)d_in[2];
    const float* b1 = (const float*)d_in[3];
    const float* W2 = (const float*)d_in[4];
    const float* b2 = (const float*)d_in[5];
    float* out = (float*)d_out;

    const int N = in_sizes[0] / 128;
    const int E = in_sizes[1] / 2;
    const int* src = ei;
    const int* dst = ei + E;
    const int NB = (N + 255) >> 8;

    char* ws = (char*)d_ws;
    size_t off = 0;
    auto alloc = [&](size_t bytes) {
        void* p = ws + off;
        off = (off + bytes + 255) & ~(size_t)255;
        return p;
    };
    float* deg_inv  = (float*)alloc((size_t)N * 4);
    int2*  se       = (int2*)alloc((size_t)N * 8);
    int*   cnt_d    = (int*)alloc((size_t)NBMAX * 16 * 4 * 2);  // cnt_d | cnt_s adjacent
    int*   cnt_s    = cnt_d + (size_t)NBMAX * 16;
    unsigned short* Wb1 = (unsigned short*)alloc((size_t)128 * 128 * 2);
    unsigned short* Wb2 = (unsigned short*)alloc((size_t)64 * 128 * 2);
    unsigned*      pairs  = (unsigned*)alloc((size_t)NBMAX * CAP * 4);
    unsigned char* srcs_b = (unsigned char*)alloc((size_t)NBMAX * CAP);
    int*   sorted_src = (int*)alloc((size_t)NBMAX * CAP * 4);
    unsigned short* h  = (unsigned short*)alloc((size_t)(N + 1) * 128 * 2);  // +1: zero pad row
    unsigned short* xb = (unsigned short*)alloc((size_t)N * 128 * 2);
    // g ((N+1) x 64 bf16) aliases pairs (dead after bucket_finalize) when it fits
    unsigned short* g = ((size_t)(N + 1) * 128 <= (size_t)NBMAX * CAP * 4)
                            ? (unsigned short*)pairs
                            : (unsigned short*)alloc((size_t)(N + 1) * 64 * 2);

    zero_cnt_kernel<<<(NBMAX * 32 + 255) / 256, 256, 0, stream>>>(cnt_d);

    const int EB = (E + CHUNK - 1) / CHUNK;
    const int NF8 = (N * 128) / 8;                     // 8-float chunks (128 % 8 == 0)
    const int WN  = 128 * 128 + 128 * 64;              // W elements to convert
    const int CB  = (NF8 + WN + 1023) / 1024;          // conversion tail blocks
    scatter2_kernel<<<2 * EB + CB, 1024, 0, stream>>>(src, dst, E, cnt_d, cnt_s,
                                                      pairs, srcs_b, NB, x, xb, NF8,
                                                      W1, W2, Wb1, Wb2);
    bucket_finalize_kernel<<<NB, 512, 0, stream>>>(pairs, srcs_b, cnt_d, cnt_s,
                                                   sorted_src, se, deg_inv, N);

    const int gblocks = (N + 63) / 64;
    const int ablocks = (N + 7) / 8;
    // layer 1: h = bf16(di * (xb @ W1))
    gemm_mfma_kernel<<<gblocks, 256, 0, stream>>>(xb, Wb1, deg_inv, h, N);
    // fused: per block, tile = relu(Agg(h)+b1)*di ; g = tile @ W2 (out1 never hits memory)
    agg128_gemm_kernel<<<ablocks, 256, 0, stream>>>(se, sorted_src, (const unsigned*)h, b1,
                                                    deg_inv, Wb2, g, N);
    // layer 2: out = Agg(g) + b2
    aggregate64_kernel<<<ablocks, 256, 0, stream>>>(se, sorted_src, (const unsigned*)g, b2, out, N);
}

// Round 10
// 261.631 us; speedup vs baseline: 1.0910x; 1.0164x over previous
//
#include <hip/hip_runtime.h>
#include <hip/hip_bf16.h>

// GCNEncoder: 2-layer GCN, out-degree norm. N=100000, E=1600000, 128->128->64, fp32 I/O.
// R19 (on R18's 265.9us): agg128_gemm runs at 2.66 TB/s gather service vs 3.55 standalone --
// the per-8-node barrier + half-zero-pad GEMM costs ~25% BW. Fix: 16 nodes per 512-thread
// block: (a) barrier amortized 2x, max-segment skew relatively smaller; (b) 16x128 tile has
// NO pad rows (GEMM is row-independent, OOR rows write zeros + guarded stores); (c) waves 0-3
// each do one 16-col output tile with K=128 (4 MFMA), waves 4-7 exit after barrier.
// Everything else identical to R18 (proven: scatter2 R14, finalize LDS-staged, W-conv tail).
// Predict: agg128_gemm 73 -> ~62-67us (gbps 2.66 -> ~3.1), FETCH/WRITE flat,
// total 265.9 -> ~255-260.

typedef __attribute__((ext_vector_type(8))) short short8;
typedef __attribute__((ext_vector_type(4))) float floatx4;

__device__ inline unsigned short f2bf(float f) {
    union { float f; unsigned u; } v; v.f = f;
    return (unsigned short)((v.u + 0x8000u) >> 16);  // round-half-away; ties p~2^-17 vs RNE
}
__device__ inline float bf2f(unsigned b) {
    union { unsigned u; float f; } v; v.u = b << 16;
    return v.f;
}
__device__ inline float bf2f_hi(unsigned b) {
    union { unsigned u; float f; } v; v.u = b & 0xFFFF0000u;
    return v.f;
}

#define NBMAX 512   // max 256-node buckets -> N <= 131072 (src < 2^24 for packing)
#define CAP   8192  // fixed bucket capacity; mean 4092 + <=768 alignment pad -> safe
#define CHUNK 8192  // edges per scatter block (R14-proven)
#define SCAP  6144  // LDS staging capacity in finalize (staged path needs cd <= SCAP-768)

// ---- zero bucket cursors (cnt_d | cnt_s contiguous: 2 * NBMAX * 16 ints) ----
__global__ __launch_bounds__(256) void zero_cnt_kernel(int* __restrict__ cnt)
{
    int i = blockIdx.x * 256 + threadIdx.x;
    if (i < NBMAX * 32) cnt[i] = 0;
}

// ---- pass 1: LDS-staged bucket partition; per-bucket run-copy write-out.
//      Blocks [0,EB): pairs by dst-bucket. [EB,2EB): src low-bytes by src-bucket.
//      Blocks >= 2EB: stream-convert x fp32 -> xb bf16, then W1/W2 -> bf16 [n][k]. ----
__global__ __launch_bounds__(1024) void scatter2_kernel(
    const int* __restrict__ src, const int* __restrict__ dst, int E,
    int* __restrict__ cnt_d, int* __restrict__ cnt_s,
    unsigned* __restrict__ pairs, unsigned char* __restrict__ srcs_b, int NB,
    const float* __restrict__ x, unsigned short* __restrict__ xb, int NF8,
    const float* __restrict__ W1, const float* __restrict__ W2,
    unsigned short* __restrict__ Wb1, unsigned short* __restrict__ Wb2)
{
    const int EB = (E + CHUNK - 1) / CHUNK;
    const int t = threadIdx.x;
    const int bid = blockIdx.x;
    if (bid >= 2 * EB) {
        int i = (bid - 2 * EB) * 1024 + t;  // 8-float chunk id
        if (i < NF8) {
            float4 a0 = ((const float4*)x)[(size_t)i * 2];
            float4 a1 = ((const float4*)x)[(size_t)i * 2 + 1];
            uint4 st;
            st.x = (unsigned)f2bf(a0.x) | ((unsigned)f2bf(a0.y) << 16);
            st.y = (unsigned)f2bf(a0.z) | ((unsigned)f2bf(a0.w) << 16);
            st.z = (unsigned)f2bf(a1.x) | ((unsigned)f2bf(a1.y) << 16);
            st.w = (unsigned)f2bf(a1.z) | ((unsigned)f2bf(a1.w) << 16);
            ((uint4*)xb)[i] = st;
        } else {
            int j = i - NF8;                 // W conversion (consumed by later kernels)
            if (j < 128 * 128) {
                int k = j >> 7, n = j & 127;
                Wb1[n * 128 + k] = f2bf(W1[k * 128 + n]);
            } else {
                j -= 128 * 128;
                if (j < 128 * 64) {
                    int k = j >> 6, n = j & 63;
                    Wb2[n * 128 + k] = f2bf(W2[k * 64 + n]);
                }
            }
        }
        return;
    }
    __shared__ int hd[NBMAX], lb[NBMAX], bd[NBMAX], cd_[NBMAX];
    __shared__ unsigned staged[CHUNK];  // 32KB; low 8KB reused as bytes in phase B
    const bool phaseA = (bid < EB);
    const int c = phaseA ? bid : bid - EB;
    const int e0 = c * CHUNK;
    const int e1 = min(e0 + CHUNK, E);
    const int* __restrict__ key = phaseA ? dst : src;

    for (int i = t; i < NB; i += 1024) { hd[i] = 0; cd_[i] = 0; }
    __syncthreads();
    for (int i = e0 + t; i < e1; i += 1024)
        atomicAdd(&hd[key[i] >> 8], 1);
    __syncthreads();
    if (t < NBMAX) lb[t] = (t < NB) ? hd[t] : 0;
    __syncthreads();
    for (int o = 1; o < NBMAX; o <<= 1) {       // inclusive scan over NBMAX entries
        int add = (t >= o && t < NBMAX) ? lb[t - o] : 0;
        __syncthreads();
        if (t < NBMAX) lb[t] += add;
        __syncthreads();
    }
    int* __restrict__ gcnt = phaseA ? cnt_d : cnt_s;
    for (int i = t; i < NB; i += 1024)
        if (hd[i]) bd[i] = atomicAdd(&gcnt[i * 16], hd[i]);
    __syncthreads();

    const int wid = t >> 6, lane = t & 63;
    if (phaseA) {
        for (int i = e0 + t; i < e1; i += 1024) {
            int sv = src[i], dv = dst[i];
            int b = dv >> 8;
            int slot = atomicAdd(&cd_[b], 1);
            staged[lb[b] - hd[b] + slot] = ((unsigned)(dv & 255) << 24) | (unsigned)sv;
        }
        __syncthreads();
        for (int b = wid; b < NB; b += 16) {    // run-copy: wave per bucket
            int len = hd[b];
            if (!len) continue;
            int start = lb[b] - len;
            size_t gbase = (size_t)b * CAP + bd[b];
            for (int j = lane; j < len; j += 64)
                pairs[gbase + j] = staged[start + j];
        }
    } else {
        unsigned char* stb = (unsigned char*)staged;
        for (int i = e0 + t; i < e1; i += 1024) {
            int sv = src[i];
            int b = sv >> 8;
            int slot = atomicAdd(&cd_[b], 1);
            stb[lb[b] - hd[b] + slot] = (unsigned char)(sv & 255);
        }
        __syncthreads();
        for (int b = wid; b < NB; b += 16) {
            int len = hd[b];
            if (!len) continue;
            int start = lb[b] - len;
            size_t gbase = (size_t)b * CAP + bd[b];
            for (int j = lane; j < len; j += 64)
                srcs_b[gbase + j] = stb[start + j];
        }
    }
}

// ---- pass 2 (fused, 512 thr): LDS-staged per-bucket dst sort (4-aligned segments,
//      pads -> dummy index N = zero row) -> sorted_src + (start,end); src hist -> deg_inv ----
__global__ __launch_bounds__(512) void bucket_finalize_kernel(
    const unsigned* __restrict__ pairs, const unsigned char* __restrict__ srcs_b,
    const int* __restrict__ cnt_d, const int* __restrict__ cnt_s,
    int* __restrict__ sorted_src, int2* __restrict__ se,
    float* __restrict__ deg_inv, int N)
{
    const int b = blockIdx.x;
    const int node0 = b << 8;
    const int t = threadIdx.x;
    const size_t base = (size_t)b * CAP;
    __shared__ int hist[256];
    __shared__ int cur[256];
    __shared__ int pre[256];
    __shared__ unsigned ps[SCAP];  // staged pairs (24KB)
    __shared__ int ss[SCAP];       // locally sorted incl. pads (24KB)

    const int cd = cnt_d[b * 16];
    const bool fits = (cd <= SCAP - 768);  // pads add up to 3*256 slots to ss[]
    if (t < 256) hist[t] = 0;
    __syncthreads();
    if (fits) {
        for (int i = t; i < cd; i += 512) {
            unsigned p = pairs[base + i];
            ps[i] = p;
            atomicAdd(&hist[p >> 24], 1);
        }
    } else {
        for (int i = t; i < cd; i += 512)
            atomicAdd(&hist[pairs[base + i] >> 24], 1);
    }
    __syncthreads();
    int v = 0, v4 = 0;
    if (t < 256) {
        v = hist[t];
        v4 = (v + 3) & ~3;  // 4-edge aligned segments (16B int4 idx loads)
        pre[t] = v4;
    }
    __syncthreads();
    for (int o = 1; o < 256; o <<= 1) {
        int add = (t >= o && t < 256) ? pre[t - o] : 0;
        __syncthreads();
        if (t < 256) pre[t] += add;
        __syncthreads();
    }
    int excl = 0;
    if (t < 256) {
        excl = pre[t] - v4;
        cur[t] = excl;
        if (node0 + t < N)
            se[node0 + t] = make_int2((int)base + excl, (int)base + excl + v);
    }
    __syncthreads();
    const int tot4 = pre[255];  // padded total (multiple of 4), <= cd + 3*256
    if (fits) {
        if (t < 256)
            for (int i = v; i < v4; ++i) ss[excl + i] = N;  // pads -> dummy zero row
        __syncthreads();
        for (int i = t; i < cd; i += 512) {
            unsigned p = ps[i];
            int pos = atomicAdd(&cur[p >> 24], 1);
            ss[pos] = (int)(p & 0xFFFFFFu);
        }
        __syncthreads();
        for (int i = t; i < tot4; i += 512)   // coalesced write-out
            sorted_src[base + i] = ss[i];
    } else {
        if (t < 256)
            for (int i = v; i < v4; ++i) sorted_src[base + excl + i] = N;
        __syncthreads();
        for (int i = t; i < cd; i += 512) {
            unsigned p = pairs[base + i];
            int pos = atomicAdd(&cur[p >> 24], 1);
            sorted_src[base + pos] = (int)(p & 0xFFFFFFu);
        }
    }

    __syncthreads();
    if (t < 256) hist[t] = 0;
    __syncthreads();
    const int cs = cnt_s[b * 16];
    for (int i = t; i < cs; i += 512)
        atomicAdd(&hist[srcs_b[base + i]], 1);
    __syncthreads();
    if (t < 256 && node0 + t < N) {
        int d = hist[t];
        deg_inv[node0 + t] = 1.0f / (float)(d < 1 ? 1 : d);
    }
}

// ---------------- MFMA GEMM (layer 1 only), no LDS ----------------
// 64 rows/block (4 waves x 16 rows). A bf16 [M x 128]. deg_inv scale in epilogue.
// Block 0 zeroes output row M (dummy row for agg pads).
__global__ __launch_bounds__(256) void gemm_mfma_kernel(
    const unsigned short* __restrict__ Ab, const unsigned short* __restrict__ Wb,
    const float* __restrict__ scale, unsigned short* __restrict__ Cb, int M)
{
    constexpr int NC = 128, NT = NC / 16;
    const int t = threadIdx.x;
    if (blockIdx.x == 0 && t < NC / 2)
        ((unsigned*)Cb)[(size_t)M * (NC / 2) + t] = 0;  // zero dummy row M
    const int wm = t >> 6;
    const int lane = t & 63;
    const int lm = lane & 15;
    const int lk = (lane >> 4) * 8;

    const int r0 = blockIdx.x * 64 + wm * 16;
    int row = r0 + lm;
    if (row >= M) row = M - 1;  // clamp loads; stores are guarded

    floatx4 acc[NT];
#pragma unroll
    for (int j = 0; j < NT; ++j) acc[j] = (floatx4){0.f, 0.f, 0.f, 0.f};

#pragma unroll
    for (int kk = 0; kk < 4; ++kk) {
        const int kb = kk * 32 + lk;
        short8 af = *(const short8*)&Ab[(size_t)row * 128 + kb];
#pragma unroll
        for (int j = 0; j < NT; ++j) {
            short8 bfr = *(const short8*)&Wb[(size_t)(j * 16 + lm) * 128 + kb];
            acc[j] = __builtin_amdgcn_mfma_f32_16x16x32_bf16(af, bfr, acc[j], 0, 0, 0);
        }
    }

    const int rbase = r0 + (lane >> 4) * 4;
#pragma unroll
    for (int reg = 0; reg < 4; ++reg) {
        int rg = rbase + reg;
        if (rg < M) {
            float di = scale[rg];
#pragma unroll
            for (int j = 0; j < NT; ++j)
                Cb[(size_t)rg * NC + j * 16 + lm] = f2bf(acc[j][reg] * di);
        }
    }
}

// ---------------- aggregate C=128 FUSED with layer-2 GEMM: 16 nodes / 512 threads ----------------
// 16 half-waves gather one node each -> 16x128 bf16 tile in LDS (XOR-swizzled, NO pad rows:
// GEMM rows are independent; OOR half-waves write zeros and stores are guarded).
// Waves 0-3: output col-tile w (16 cols), K=128 (4 MFMA). Waves 4-7 exit after barrier.
#define LD128(vv, ii) uint2 vv = *(const uint2*)&val[(size_t)(ii) * 64 + 2 * l]
#define ACC8_128(I0, I1) do { \
    LD128(v0, I0.x); LD128(v1, I0.y); LD128(v2, I0.z); LD128(v3, I0.w); \
    LD128(v4, I1.x); LD128(v5, I1.y); LD128(v6, I1.z); LD128(v7, I1.w); \
    a0 += ((bf2f(v0.x & 0xFFFF) + bf2f(v1.x & 0xFFFF)) + (bf2f(v2.x & 0xFFFF) + bf2f(v3.x & 0xFFFF))) \
        + ((bf2f(v4.x & 0xFFFF) + bf2f(v5.x & 0xFFFF)) + (bf2f(v6.x & 0xFFFF) + bf2f(v7.x & 0xFFFF))); \
    a1 += ((bf2f_hi(v0.x) + bf2f_hi(v1.x)) + (bf2f_hi(v2.x) + bf2f_hi(v3.x))) \
        + ((bf2f_hi(v4.x) + bf2f_hi(v5.x)) + (bf2f_hi(v6.x) + bf2f_hi(v7.x))); \
    a2 += ((bf2f(v0.y & 0xFFFF) + bf2f(v1.y & 0xFFFF)) + (bf2f(v2.y & 0xFFFF) + bf2f(v3.y & 0xFFFF))) \
        + ((bf2f(v4.y & 0xFFFF) + bf2f(v5.y & 0xFFFF)) + (bf2f(v6.y & 0xFFFF) + bf2f(v7.y & 0xFFFF))); \
    a3 += ((bf2f_hi(v0.y) + bf2f_hi(v1.y)) + (bf2f_hi(v2.y) + bf2f_hi(v3.y))) \
        + ((bf2f_hi(v4.y) + bf2f_hi(v5.y)) + (bf2f_hi(v6.y) + bf2f_hi(v7.y))); \
} while (0)
#define ACC4_128(I0) do { \
    LD128(v0, I0.x); LD128(v1, I0.y); LD128(v2, I0.z); LD128(v3, I0.w); \
    a0 += (bf2f(v0.x & 0xFFFF) + bf2f(v1.x & 0xFFFF)) + (bf2f(v2.x & 0xFFFF) + bf2f(v3.x & 0xFFFF)); \
    a1 += (bf2f_hi(v0.x) + bf2f_hi(v1.x)) + (bf2f_hi(v2.x) + bf2f_hi(v3.x)); \
    a2 += (bf2f(v0.y & 0xFFFF) + bf2f(v1.y & 0xFFFF)) + (bf2f(v2.y & 0xFFFF) + bf2f(v3.y & 0xFFFF)); \
    a3 += (bf2f_hi(v0.y) + bf2f_hi(v1.y)) + (bf2f_hi(v2.y) + bf2f_hi(v3.y)); \
} while (0)

__global__ __launch_bounds__(512) void agg128_gemm_kernel(
    const int2* __restrict__ se, const int* __restrict__ sorted_src,
    const unsigned* __restrict__ val, const float* __restrict__ bias,
    const float* __restrict__ deg_inv, const unsigned short* __restrict__ Wb2,
    unsigned short* __restrict__ g, int N)
{
    __shared__ unsigned short tile[16 * 128];  // 4KB, all 16 rows real
    const int t = threadIdx.x;
    if (blockIdx.x == 0 && t < 32) ((unsigned*)g)[(size_t)N * 32 + t] = 0;  // dummy row N

    const int hw = t >> 5;                     // half-wave = node row 0..15
    const int l = t & 31;
    const int node = blockIdx.x * 16 + hw;
    float a0 = 0.f, a1 = 0.f, a2 = 0.f, a3 = 0.f;
    if (node < N) {
        int2 r = se[node];
        int e = r.x;
        const int end4 = r.x + ((r.y - r.x + 3) & ~3);  // pads -> zero row
        if (e + 8 <= end4) {
            int4 i0 = *(const int4*)&sorted_src[e];
            int4 i1 = *(const int4*)&sorted_src[e + 4];
            for (; e + 16 <= end4; e += 8) {
                int4 n0 = *(const int4*)&sorted_src[e + 8];
                int4 n1 = *(const int4*)&sorted_src[e + 12];
                ACC8_128(i0, i1);
                i0 = n0; i1 = n1;
            }
            ACC8_128(i0, i1);
            e += 8;
        }
        if (e < end4) {  // exactly 4 remain
            int4 i0 = *(const int4*)&sorted_src[e];
            ACC4_128(i0);
        }
        float di = deg_inv[node];
        float4 bv = *(const float4*)&bias[4 * l];
        a0 = fmaxf(a0 + bv.x, 0.f) * di;
        a1 = fmaxf(a1 + bv.y, 0.f) * di;
        a2 = fmaxf(a2 + bv.z, 0.f) * di;
        a3 = fmaxf(a3 + bv.w, 0.f) * di;
    }
    // stage bf16 tile row hw, channels 4l..4l+3; 16B blocks XOR-swizzled by row:
    // linear blk (l>>1) stored at ((l>>1) ^ hw) & 15; inner 8B half = l&1.
    {
        unsigned w0 = (unsigned)f2bf(a0) | ((unsigned)f2bf(a1) << 16);
        unsigned w1 = (unsigned)f2bf(a2) | ((unsigned)f2bf(a3) << 16);
        unsigned* p = (unsigned*)&tile[hw * 128 + ((((l >> 1) ^ hw) & 15) << 3) + (l & 1) * 4];
        p[0] = w0;
        p[1] = w1;
    }
    __syncthreads();

    // mini-GEMM: wave w (0..3) -> output cols [16w,16w+16), rows 0..15 all real
    const int w = t >> 6;
    if (w < 4) {
        const int lane = t & 63;
        const int lm = lane & 15;
        const int lk = (lane >> 4) * 8;
        floatx4 acc = (floatx4){0.f, 0.f, 0.f, 0.f};
#pragma unroll
        for (int kk = 0; kk < 4; ++kk) {
            const int kb = kk * 32 + lk;
            const int blk = ((kb >> 3) ^ lm) & 15;   // un-swizzle A read
            short8 af = *(const short8*)&tile[lm * 128 + (blk << 3)];
            short8 bfr = *(const short8*)&Wb2[(size_t)(w * 16 + lm) * 128 + kb];
            acc = __builtin_amdgcn_mfma_f32_16x16x32_bf16(af, bfr, acc, 0, 0, 0);
        }
        const int rbase = (lane >> 4) * 4;
#pragma unroll
        for (int reg = 0; reg < 4; ++reg) {
            int r = rbase + reg;
            int nd = blockIdx.x * 16 + r;
            if (nd < N) g[(size_t)nd * 64 + w * 16 + lm] = f2bf(acc[reg]);
        }
    }
}

// ---------------- aggregate C=64 (bf16 in, fp32 out, +bias): 8-edge unroll + idx prefetch ----------------
#define LD64(vv, ii) unsigned vv = val[(size_t)(ii) * 32 + l]
#define ACC8_64(I0, I1) do { \
    LD64(v0, I0.x); LD64(v1, I0.y); LD64(v2, I0.z); LD64(v3, I0.w); \
    LD64(v4, I1.x); LD64(v5, I1.y); LD64(v6, I1.z); LD64(v7, I1.w); \
    ax += ((bf2f(v0 & 0xFFFF) + bf2f(v1 & 0xFFFF)) + (bf2f(v2 & 0xFFFF) + bf2f(v3 & 0xFFFF))) \
        + ((bf2f(v4 & 0xFFFF) + bf2f(v5 & 0xFFFF)) + (bf2f(v6 & 0xFFFF) + bf2f(v7 & 0xFFFF))); \
    ay += ((bf2f_hi(v0) + bf2f_hi(v1)) + (bf2f_hi(v2) + bf2f_hi(v3))) \
        + ((bf2f_hi(v4) + bf2f_hi(v5)) + (bf2f_hi(v6) + bf2f_hi(v7))); \
} while (0)
#define ACC4_64(I0) do { \
    LD64(v0, I0.x); LD64(v1, I0.y); LD64(v2, I0.z); LD64(v3, I0.w); \
    ax += (bf2f(v0 & 0xFFFF) + bf2f(v1 & 0xFFFF)) + (bf2f(v2 & 0xFFFF) + bf2f(v3 & 0xFFFF)); \
    ay += (bf2f_hi(v0) + bf2f_hi(v1)) + (bf2f_hi(v2) + bf2f_hi(v3)); \
} while (0)

__global__ __launch_bounds__(256) void aggregate64_kernel(
    const int2* __restrict__ se, const int* __restrict__ sorted_src,
    const unsigned* __restrict__ val, const float* __restrict__ bias,
    float* __restrict__ out, int N)
{
    int node = blockIdx.x * 8 + (threadIdx.x >> 5);
    if (node >= N) return;
    int l = threadIdx.x & 31;
    int2 r = se[node];
    int e = r.x;
    const int end4 = r.x + ((r.y - r.x + 3) & ~3);
    float ax = 0.f, ay = 0.f;

    if (e + 8 <= end4) {
        int4 i0 = *(const int4*)&sorted_src[e];
        int4 i1 = *(const int4*)&sorted_src[e + 4];
        for (; e + 16 <= end4; e += 8) {
            int4 n0 = *(const int4*)&sorted_src[e + 8];
            int4 n1 = *(const int4*)&sorted_src[e + 12];
            ACC8_64(i0, i1);
            i0 = n0; i1 = n1;
        }
        ACC8_64(i0, i1);
        e += 8;
    }
    if (e < end4) {
        int4 i0 = *(const int4*)&sorted_src[e];
        ACC4_64(i0);
    }

    float2 o = make_float2(ax + bias[2 * l], ay + bias[2 * l + 1]);
    *(float2*)&out[(size_t)node * 64 + 2 * l] = o;
}

extern "C" void kernel_launch(void* const* d_in, const int* in_sizes, int n_in,
                              void* d_out, int out_size, void* d_ws, size_t ws_size,
                              hipStream_t stream) {
    const float* x  = (const float*)d_in[0];
    const int*   ei = (const int*)d_in[1];
    const float* W1 = (const float*)d_in[2];
    const float* b1 = (const float*)d_in[3];
    const float* W2 = (const float*)d_in[4];
    const float* b2 = (const float*)d_in[5];
    float* out = (float*)d_out;

    const int N = in_sizes[0] / 128;
    const int E = in_sizes[1] / 2;
    const int* src = ei;
    const int* dst = ei + E;
    const int NB = (N + 255) >> 8;

    char* ws = (char*)d_ws;
    size_t off = 0;
    auto alloc = [&](size_t bytes) {
        void* p = ws + off;
        off = (off + bytes + 255) & ~(size_t)255;
        return p;
    };
    float* deg_inv  = (float*)alloc((size_t)N * 4);
    int2*  se       = (int2*)alloc((size_t)N * 8);
    int*   cnt_d    = (int*)alloc((size_t)NBMAX * 16 * 4 * 2);  // cnt_d | cnt_s adjacent
    int*   cnt_s    = cnt_d + (size_t)NBMAX * 16;
    unsigned short* Wb1 = (unsigned short*)alloc((size_t)128 * 128 * 2);
    unsigned short* Wb2 = (unsigned short*)alloc((size_t)64 * 128 * 2);
    unsigned*      pairs  = (unsigned*)alloc((size_t)NBMAX * CAP * 4);
    unsigned char* srcs_b = (unsigned char*)alloc((size_t)NBMAX * CAP);
    int*   sorted_src = (int*)alloc((size_t)NBMAX * CAP * 4);
    unsigned short* h  = (unsigned short*)alloc((size_t)(N + 1) * 128 * 2);  // +1: zero pad row
    unsigned short* xb = (unsigned short*)alloc((size_t)N * 128 * 2);
    // g ((N+1) x 64 bf16) aliases pairs (dead after bucket_finalize) when it fits
    unsigned short* g = ((size_t)(N + 1) * 128 <= (size_t)NBMAX * CAP * 4)
                            ? (unsigned short*)pairs
                            : (unsigned short*)alloc((size_t)(N + 1) * 64 * 2);

    zero_cnt_kernel<<<(NBMAX * 32 + 255) / 256, 256, 0, stream>>>(cnt_d);

    const int EB = (E + CHUNK - 1) / CHUNK;
    const int NF8 = (N * 128) / 8;                     // 8-float chunks (128 % 8 == 0)
    const int WN  = 128 * 128 + 128 * 64;              // W elements to convert
    const int CB  = (NF8 + WN + 1023) / 1024;          // conversion tail blocks
    scatter2_kernel<<<2 * EB + CB, 1024, 0, stream>>>(src, dst, E, cnt_d, cnt_s,
                                                      pairs, srcs_b, NB, x, xb, NF8,
                                                      W1, W2, Wb1, Wb2);
    bucket_finalize_kernel<<<NB, 512, 0, stream>>>(pairs, srcs_b, cnt_d, cnt_s,
                                                   sorted_src, se, deg_inv, N);

    const int gblocks = (N + 63) / 64;
    const int fblocks = (N + 15) / 16;
    const int ablocks = (N + 7) / 8;
    // layer 1: h = bf16(di * (xb @ W1))
    gemm_mfma_kernel<<<gblocks, 256, 0, stream>>>(xb, Wb1, deg_inv, h, N);
    // fused: per block, 16-row tile = relu(Agg(h)+b1)*di ; g = tile @ W2
    agg128_gemm_kernel<<<fblocks, 512, 0, stream>>>(se, sorted_src, (const unsigned*)h, b1,
                                                    deg_inv, Wb2, g, N);
    // layer 2: out = Agg(g) + b2
    aggregate64_kernel<<<ablocks, 256, 0, stream>>>(se, sorted_src, (const unsigned*)g, b2, out, N);
}